// Round 2
// baseline (880.209 us; speedup 1.0000x reference)
//
#include <hip/hip_runtime.h>
#include <hip/hip_bf16.h>

typedef __hip_bfloat16 bf16;

static constexpr int N_NODES = 100000;
static constexpr int N_EDGES = 3200000;
static constexpr int F_IN    = 54;
static constexpr int F_HID   = 16;

// bucket path
static constexpr int BSHIFT    = 7;                  // 128 nodes per bucket
static constexpr int BNODES    = 128;
static constexpr int NBUCK     = (N_NODES + BNODES - 1) / BNODES;  // 782
static constexpr int CAP_B     = 5120;
static constexpr int BIN_CHUNK = 8192;
static constexpr int GRDB      = (N_EDGES + BIN_CHUNK - 1) / BIN_CHUNK;  // 391
static constexpr int GRDN_F    = (N_NODES + 1023) / 1024;                // 98

// ---------------------------------------------------------------------------
// ws layout (float indices) — unchanged from the 258-us round (srcs region now
// unused but offsets kept identical).
// hc1/hc2: combined per-node 64-B rows, dword k = bf16(h[k]) | bf16(a_src)<<16
// ---------------------------------------------------------------------------
static constexpr size_t WS_FLAGS  = 0;        // 4 ints
static constexpr size_t WS_ADST   = 4;        // 100000
static constexpr size_t WS_ADST2  = 100004;   // 100000
static constexpr size_t WS_BCNT   = 200004;   // 1024 ints
static constexpr size_t WS_ROWBEG = 201028;   // 100000 ints (unused)
static constexpr size_t WS_ROWCNT = 301028;   // 100000 ints (unused)
static constexpr size_t WS_HC1    = 401028;   // 1,600,000 dw
static constexpr size_t WS_HC2    = 2001028;  // 1,600,000 dw
static constexpr size_t WS_BEDGES = 3601028;  // NBUCK*CAP_B ints
static constexpr size_t WS_SRCS   = 7604868;  // NBUCK*CAP_B ints (unused)
static constexpr size_t WS_BUCKET_END = WS_SRCS + (size_t)NBUCK * CAP_B; // 11,608,708
static constexpr size_t WS_FB_DEN     = 3601028;
static constexpr size_t WS_FB_AS      = 3701028;
static constexpr size_t WS_ATOMIC_END = 3801028;

__device__ __forceinline__ float lrelu(float v) { return fmaxf(v, 0.2f * v); }
__device__ __forceinline__ float loadf(const void* p, int i, bool f32) {
    return f32 ? ((const float*)p)[i] : __bfloat162float(((const bf16*)p)[i]);
}
__device__ __forceinline__ unsigned f2bf(float f) {   // RNE fp32->bf16 bits
    unsigned u = __float_as_uint(f);
    return (u + 0x7FFFu + ((u >> 16) & 1u)) >> 16;
}

// ---------------------------------------------------------------------------
// Probe (+ zero bcnt): bit0 = floats fp32 ; bit1 = edge_index int64
// ---------------------------------------------------------------------------
__global__ __launch_bounds__(256) void k_probe0(
    const void* __restrict__ x, const void* __restrict__ ei,
    int* __restrict__ flags, int* __restrict__ bcnt)
{
    __shared__ int cnt, nz;
    const int t = threadIdx.x;
    if (t == 0) { cnt = 0; nz = 0; }
    __syncthreads();
    const unsigned u = ((const unsigned*)x)[t];
    if ((u & 0x7FFFu) >= 0x4800u) atomicAdd(&cnt, 1);
    if (t < 64) {
        if (((const unsigned*)ei)[2 * t + 1] != 0u) atomicAdd(&nz, 1);
    }
    for (int i = t; i < 1024; i += 256) bcnt[i] = 0;
    __syncthreads();
    if (t == 0) flags[0] = ((cnt >= 16) ? 1 : 0) | ((nz == 0) ? 2 : 0);
}

// ---------------------------------------------------------------------------
// k_binfeat (1024 thr): [0,GRDB) bin w/ LDS edge cache; [GRDB,+GRDN_F) feat1:
// h1 = x@W1 (fp32 regs); emits combined row dword k = bf16(h[k])|bf16(a)<<16.
// ---------------------------------------------------------------------------
__global__ __launch_bounds__(1024, 8) void k_binfeat(
    const void* __restrict__ ei, const void* __restrict__ x,
    const void* __restrict__ W1, const void* __restrict__ a_s,
    const void* __restrict__ a_d, const int* __restrict__ flags,
    int* __restrict__ bcnt, int* __restrict__ bedges,
    unsigned* __restrict__ hc, float* __restrict__ adst)
{
    __shared__ int            hist[NBUCK];
    __shared__ int            base[NBUCK];
    __shared__ int            cval[BIN_CHUNK];
    __shared__ unsigned short cbkt[BIN_CHUNK];
    __shared__ float Wl[F_IN * F_HID];
    __shared__ float asl[F_HID];
    __shared__ float adl[F_HID];
    const int t = threadIdx.x;
    const bool f32 = flags[0] & 1;
    const bool i64 = flags[0] & 2;

    if (blockIdx.x < GRDB) {
        const int e0 = blockIdx.x * BIN_CHUNK;
        const int valid = min(BIN_CHUNK, N_EDGES - e0);
        for (int i = t; i < NBUCK; i += 1024) hist[i] = 0;
        __syncthreads();
#pragma unroll
        for (int i = 0; i < BIN_CHUNK / 1024; ++i) {
            const int idx = i * 1024 + t;
            const int e = e0 + idx;
            if (idx < valid) {
                int s, d;
                if (i64) {
                    s = ((const int*)ei)[2 * (size_t)e];
                    d = ((const int*)ei)[2 * ((size_t)N_EDGES + e)];
                } else {
                    s = ((const int*)ei)[e];
                    d = ((const int*)ei)[(size_t)N_EDGES + e];
                }
                const int b = d >> BSHIFT;
                cval[idx] = (s << BSHIFT) | (d & (BNODES - 1));
                cbkt[idx] = (unsigned short)b;
                atomicAdd(&hist[b], 1);
            }
        }
        __syncthreads();
        for (int i = t; i < NBUCK; i += 1024) {
            const int c = hist[i];
            base[i] = c ? atomicAdd(&bcnt[i], c) : 0;
            hist[i] = 0;
        }
        __syncthreads();
#pragma unroll
        for (int i = 0; i < BIN_CHUNK / 1024; ++i) {
            const int idx = i * 1024 + t;
            if (idx < valid) {
                const int b = cbkt[idx];
                const int r = atomicAdd(&hist[b], 1);
                const int pos = base[b] + r;
                if (pos < CAP_B) bedges[(size_t)b * CAP_B + pos] = cval[idx];
            }
        }
    } else {
        for (int i = t; i < F_IN * F_HID; i += 1024) Wl[i] = loadf(W1, i, f32);
        if (t < F_HID) { asl[t] = loadf(a_s, t, f32); adl[t] = loadf(a_d, t, f32); }
        __syncthreads();
        const int node = (blockIdx.x - GRDB) * 1024 + t;
        if (node >= N_NODES) return;

        float h[F_HID];
#pragma unroll
        for (int k = 0; k < F_HID; ++k) h[k] = 0.f;
        if (f32) {
            const float2* xp = (const float2*)((const float*)x + (size_t)node * F_IN);
#pragma unroll
            for (int j = 0; j < F_IN / 2; ++j) {
                const float2 v = xp[j];
#pragma unroll
                for (int k = 0; k < F_HID; ++k) {
                    h[k] = fmaf(v.x, Wl[(2*j)   * F_HID + k], h[k]);
                    h[k] = fmaf(v.y, Wl[(2*j+1) * F_HID + k], h[k]);
                }
            }
        } else {
            const unsigned* xu = (const unsigned*)x + (size_t)node * (F_IN / 2);
#pragma unroll
            for (int j = 0; j < F_IN / 2; ++j) {
                const unsigned u = xu[j];
                const float v0 = __uint_as_float(u << 16);
                const float v1 = __uint_as_float(u & 0xFFFF0000u);
#pragma unroll
                for (int k = 0; k < F_HID; ++k) {
                    h[k] = fmaf(v0, Wl[(2*j)   * F_HID + k], h[k]);
                    h[k] = fmaf(v1, Wl[(2*j+1) * F_HID + k], h[k]);
                }
            }
        }
        float s = 0.f, d = 0.f;
#pragma unroll
        for (int k = 0; k < F_HID; ++k) { s = fmaf(h[k], asl[k], s); d = fmaf(h[k], adl[k], d); }
        adst[node] = d;
        const unsigned ab = f2bf(s) << 16;
        unsigned pk[F_HID];
#pragma unroll
        for (int k = 0; k < F_HID; ++k) pk[k] = f2bf(h[k]) | ab;
        uint4* hb = (uint4*)(hc + (size_t)node * F_HID);
#pragma unroll
        for (int q = 0; q < 4; ++q)
            hb[q] = make_uint4(pk[4*q], pk[4*q+1], pk[4*q+2], pk[4*q+3]);
    }
}

// ---------------------------------------------------------------------------
// k_agg1 (NEW): one block per bucket, LDS-atomic accumulation directly from the
// UNSORTED bucket edge list (bedges). Eliminates k_bsort + srcs entirely.
// 16 lanes per edge, one dword gather per edge (4 cachelines / wave instr).
// acc padded *17 to spread LDS banks. Epilogue fuses ELU + z@W2 (width-16
// shuffles) and emits the layer-2 combined row + adst2.
// ---------------------------------------------------------------------------
__global__ __launch_bounds__(512, 4) void k_agg1(
    const int* __restrict__ bcnt, const int* __restrict__ bedges,
    const float* __restrict__ adst, const unsigned* __restrict__ hc,
    const void* __restrict__ b1, const void* __restrict__ W2,
    const void* __restrict__ a_s2, const void* __restrict__ a_d2,
    const int* __restrict__ flags,
    unsigned* __restrict__ hc2, float* __restrict__ adst2)
{
    __shared__ float Wl[F_HID * F_HID];
    __shared__ float asl[F_HID], adl[F_HID], bl[F_HID];
    __shared__ float adL[BNODES];
    __shared__ float accL[BNODES * 17];
    __shared__ float denL[BNODES];
    const bool f32 = flags[0] & 1;
    const int t = threadIdx.x;
    const int b = blockIdx.x;
    const int n0 = b << BSHIFT;
    if (t < F_HID * F_HID) Wl[t] = loadf(W2, t, f32);
    if (t < F_HID) {
        asl[t] = loadf(a_s2, t, f32);
        adl[t] = loadf(a_d2, t, f32);
        bl[t]  = loadf(b1, t, f32);
    }
    if (t < BNODES) {
        const int node = n0 + t;
        adL[t] = (node < N_NODES) ? adst[node] : 0.f;
    }
    __syncthreads();

    const int k    = t & 15;
    const int slot = t >> 4;                     // 0..31
    // ---- init with self-loop term (single writer per slot, no atomics) ----
#pragma unroll
    for (int it = 0; it < 4; ++it) {
        const int dl = it * 32 + slot;
        const int node = n0 + dl;
        if (node < N_NODES) {
            const unsigned vs = hc[((size_t)node << 4) + k];
            const float w0 = __expf(lrelu(__uint_as_float(vs & 0xFFFF0000u) + adL[dl]));
            accL[dl * 17 + k] = w0 * __uint_as_float(vs << 16);
            if (k == 0) denL[dl] = w0;
        } else {
            accL[dl * 17 + k] = 0.f;
            if (k == 0) denL[dl] = 1.f;
        }
    }
    __syncthreads();

    // ---- edge accumulation (unsorted list, LDS float atomics) ----
    const int cnt = min(bcnt[b], CAP_B);
    const int* cv = bedges + (size_t)b * CAP_B;
    int e = slot;
    for (; e + 96 < cnt; e += 128) {
        const int p0 = cv[e], p1 = cv[e + 32], p2 = cv[e + 64], p3 = cv[e + 96];
        const int d0 = p0 & 127, d1 = p1 & 127, d2 = p2 & 127, d3 = p3 & 127;
        const unsigned v0 = hc[((size_t)(p0 >> 7) << 4) + k];
        const unsigned v1 = hc[((size_t)(p1 >> 7) << 4) + k];
        const unsigned v2 = hc[((size_t)(p2 >> 7) << 4) + k];
        const unsigned v3 = hc[((size_t)(p3 >> 7) << 4) + k];
        const float w0 = __expf(lrelu(__uint_as_float(v0 & 0xFFFF0000u) + adL[d0]));
        const float w1 = __expf(lrelu(__uint_as_float(v1 & 0xFFFF0000u) + adL[d1]));
        const float w2 = __expf(lrelu(__uint_as_float(v2 & 0xFFFF0000u) + adL[d2]));
        const float w3 = __expf(lrelu(__uint_as_float(v3 & 0xFFFF0000u) + adL[d3]));
        atomicAdd(&accL[d0 * 17 + k], w0 * __uint_as_float(v0 << 16));
        atomicAdd(&accL[d1 * 17 + k], w1 * __uint_as_float(v1 << 16));
        atomicAdd(&accL[d2 * 17 + k], w2 * __uint_as_float(v2 << 16));
        atomicAdd(&accL[d3 * 17 + k], w3 * __uint_as_float(v3 << 16));
        if (k == 0) {
            atomicAdd(&denL[d0], w0);
            atomicAdd(&denL[d1], w1);
            atomicAdd(&denL[d2], w2);
            atomicAdd(&denL[d3], w3);
        }
    }
    for (; e < cnt; e += 32) {
        const int p = cv[e];
        const int dl = p & 127;
        const unsigned v = hc[((size_t)(p >> 7) << 4) + k];
        const float w = __expf(lrelu(__uint_as_float(v & 0xFFFF0000u) + adL[dl]));
        atomicAdd(&accL[dl * 17 + k], w * __uint_as_float(v << 16));
        if (k == 0) atomicAdd(&denL[dl], w);
    }
    __syncthreads();

    // ---- epilogue: softmax divide + ELU + z@W2 + layer-2 attn logits ----
#pragma unroll
    for (int it = 0; it < 4; ++it) {
        const int dl = it * 32 + slot;
        const int node = n0 + dl;
        if (node >= N_NODES) continue;            // group-uniform guard
        float z = accL[dl * 17 + k] / denL[dl] + bl[k];
        z = z > 0.f ? z : expm1f(z);
        float hh = 0.f;
#pragma unroll
        for (int j = 0; j < F_HID; ++j) {
            const float zj = __shfl(z, j, 16);
            hh = fmaf(zj, Wl[j * F_HID + k], hh);
        }
        float s2 = hh * asl[k], d2v = hh * adl[k];
#pragma unroll
        for (int off = 1; off < 16; off <<= 1) {
            s2  += __shfl_xor(s2, off, 16);
            d2v += __shfl_xor(d2v, off, 16);
        }
        hc2[((size_t)node << 4) + k] = f2bf(hh) | (f2bf(s2) << 16);
        if (k == 0) adst2[node] = d2v;
    }
}

// ---------------------------------------------------------------------------
// k_agg2 (NEW): same per-bucket LDS-atomic aggregation on layer-2 rows;
// writes fp32 out (contiguous 8 KB per bucket).
// ---------------------------------------------------------------------------
__global__ __launch_bounds__(512, 4) void k_agg2(
    const int* __restrict__ bcnt, const int* __restrict__ bedges,
    const float* __restrict__ adst, const unsigned* __restrict__ hc,
    const void* __restrict__ b2, const int* __restrict__ flags,
    float* __restrict__ outp)
{
    __shared__ float bl[F_HID];
    __shared__ float adL[BNODES];
    __shared__ float accL[BNODES * 17];
    __shared__ float denL[BNODES];
    const bool f32 = flags[0] & 1;
    const int t = threadIdx.x;
    const int b = blockIdx.x;
    const int n0 = b << BSHIFT;
    if (t < F_HID) bl[t] = loadf(b2, t, f32);
    if (t < BNODES) {
        const int node = n0 + t;
        adL[t] = (node < N_NODES) ? adst[node] : 0.f;
    }
    __syncthreads();

    const int k    = t & 15;
    const int slot = t >> 4;
#pragma unroll
    for (int it = 0; it < 4; ++it) {
        const int dl = it * 32 + slot;
        const int node = n0 + dl;
        if (node < N_NODES) {
            const unsigned vs = hc[((size_t)node << 4) + k];
            const float w0 = __expf(lrelu(__uint_as_float(vs & 0xFFFF0000u) + adL[dl]));
            accL[dl * 17 + k] = w0 * __uint_as_float(vs << 16);
            if (k == 0) denL[dl] = w0;
        } else {
            accL[dl * 17 + k] = 0.f;
            if (k == 0) denL[dl] = 1.f;
        }
    }
    __syncthreads();

    const int cnt = min(bcnt[b], CAP_B);
    const int* cv = bedges + (size_t)b * CAP_B;
    int e = slot;
    for (; e + 96 < cnt; e += 128) {
        const int p0 = cv[e], p1 = cv[e + 32], p2 = cv[e + 64], p3 = cv[e + 96];
        const int d0 = p0 & 127, d1 = p1 & 127, d2 = p2 & 127, d3 = p3 & 127;
        const unsigned v0 = hc[((size_t)(p0 >> 7) << 4) + k];
        const unsigned v1 = hc[((size_t)(p1 >> 7) << 4) + k];
        const unsigned v2 = hc[((size_t)(p2 >> 7) << 4) + k];
        const unsigned v3 = hc[((size_t)(p3 >> 7) << 4) + k];
        const float w0 = __expf(lrelu(__uint_as_float(v0 & 0xFFFF0000u) + adL[d0]));
        const float w1 = __expf(lrelu(__uint_as_float(v1 & 0xFFFF0000u) + adL[d1]));
        const float w2 = __expf(lrelu(__uint_as_float(v2 & 0xFFFF0000u) + adL[d2]));
        const float w3 = __expf(lrelu(__uint_as_float(v3 & 0xFFFF0000u) + adL[d3]));
        atomicAdd(&accL[d0 * 17 + k], w0 * __uint_as_float(v0 << 16));
        atomicAdd(&accL[d1 * 17 + k], w1 * __uint_as_float(v1 << 16));
        atomicAdd(&accL[d2 * 17 + k], w2 * __uint_as_float(v2 << 16));
        atomicAdd(&accL[d3 * 17 + k], w3 * __uint_as_float(v3 << 16));
        if (k == 0) {
            atomicAdd(&denL[d0], w0);
            atomicAdd(&denL[d1], w1);
            atomicAdd(&denL[d2], w2);
            atomicAdd(&denL[d3], w3);
        }
    }
    for (; e < cnt; e += 32) {
        const int p = cv[e];
        const int dl = p & 127;
        const unsigned v = hc[((size_t)(p >> 7) << 4) + k];
        const float w = __expf(lrelu(__uint_as_float(v & 0xFFFF0000u) + adL[dl]));
        atomicAdd(&accL[dl * 17 + k], w * __uint_as_float(v << 16));
        if (k == 0) atomicAdd(&denL[dl], w);
    }
    __syncthreads();

#pragma unroll
    for (int it = 0; it < 4; ++it) {
        const int dl = it * 32 + slot;
        const int node = n0 + dl;
        if (node >= N_NODES) continue;
        outp[((size_t)node << 4) + k] = accL[dl * 17 + k] / denL[dl] + bl[k];
    }
}

// ---------------------------------------------------------------------------
// Fallback kernels (round-3 proven atomic path, fp32 buffers) + diag
// ---------------------------------------------------------------------------
__global__ __launch_bounds__(256) void k_feat1(
    const void* __restrict__ x, const void* __restrict__ W1,
    const void* __restrict__ a_s, const void* __restrict__ a_d,
    const int* __restrict__ flags,
    float* __restrict__ hbuf, float* __restrict__ asrc, float* __restrict__ adst)
{
    const bool f32 = flags[0] & 1;
    __shared__ float Wl[F_IN * F_HID];
    __shared__ float asl[F_HID];
    __shared__ float adl[F_HID];
    const int t = threadIdx.x;
    for (int i = t; i < F_IN * F_HID; i += 256) Wl[i] = loadf(W1, i, f32);
    if (t < F_HID) { asl[t] = loadf(a_s, t, f32); adl[t] = loadf(a_d, t, f32); }
    __syncthreads();
    const int node = blockIdx.x * 256 + t;
    if (node >= N_NODES) return;
    float h[F_HID];
#pragma unroll
    for (int k = 0; k < F_HID; ++k) h[k] = 0.f;
    if (f32) {
        const float2* xp = (const float2*)((const float*)x + (size_t)node * F_IN);
#pragma unroll
        for (int j = 0; j < F_IN / 2; ++j) {
            const float2 v = xp[j];
#pragma unroll
            for (int k = 0; k < F_HID; ++k) {
                h[k] = fmaf(v.x, Wl[(2*j)   * F_HID + k], h[k]);
                h[k] = fmaf(v.y, Wl[(2*j+1) * F_HID + k], h[k]);
            }
        }
    } else {
        const unsigned* xu = (const unsigned*)x + (size_t)node * (F_IN / 2);
#pragma unroll
        for (int j = 0; j < F_IN / 2; ++j) {
            const unsigned u = xu[j];
            const float v0 = __uint_as_float(u << 16);
            const float v1 = __uint_as_float(u & 0xFFFF0000u);
#pragma unroll
            for (int k = 0; k < F_HID; ++k) {
                h[k] = fmaf(v0, Wl[(2*j)   * F_HID + k], h[k]);
                h[k] = fmaf(v1, Wl[(2*j+1) * F_HID + k], h[k]);
            }
        }
    }
    float s = 0.f, d = 0.f;
#pragma unroll
    for (int k = 0; k < F_HID; ++k) { s = fmaf(h[k], asl[k], s); d = fmaf(h[k], adl[k], d); }
    asrc[node] = s; adst[node] = d;
    float4* hb = (float4*)(hbuf + (size_t)node * F_HID);
#pragma unroll
    for (int q = 0; q < 4; ++q)
        hb[q] = make_float4(h[4*q], h[4*q+1], h[4*q+2], h[4*q+3]);
}

__global__ __launch_bounds__(256) void k_selfinit(
    const float* __restrict__ asrc, const float* __restrict__ adst,
    const float* __restrict__ h, float* __restrict__ denom, float* __restrict__ acc)
{
    const int t = blockIdx.x * 256 + threadIdx.x;
    if (t >= N_NODES * F_HID) return;
    const int n = t >> 4;
    const float w0 = __expf(lrelu(asrc[n] + adst[n]));
    if ((t & 15) == 0) denom[n] = w0;
    acc[t] = w0 * h[t];
}

__global__ __launch_bounds__(256) void k_edge(
    const void* __restrict__ ei, const int* __restrict__ flags,
    const float* __restrict__ asrc, const float* __restrict__ adst,
    const float* __restrict__ hbuf,
    float* __restrict__ denom, float* __restrict__ acc)
{
    const int e = blockIdx.x * 256 + threadIdx.x;
    if (e >= N_EDGES) return;
    int s, d;
    if (flags[0] & 2) {
        const long long* e64 = (const long long*)ei;
        s = (int)e64[e]; d = (int)e64[(size_t)N_EDGES + e];
    } else {
        const int* e32 = (const int*)ei;
        s = e32[e]; d = e32[(size_t)N_EDGES + e];
    }
    const float w = __expf(lrelu(asrc[s] + adst[d]));
    atomicAdd(&denom[d], w);
    const float4* hs = (const float4*)(hbuf + (size_t)s * F_HID);
    float* ad = acc + (size_t)d * F_HID;
#pragma unroll
    for (int q = 0; q < 4; ++q) {
        const float4 hv = hs[q];
        atomicAdd(ad + 4*q + 0, w * hv.x);
        atomicAdd(ad + 4*q + 1, w * hv.y);
        atomicAdd(ad + 4*q + 2, w * hv.z);
        atomicAdd(ad + 4*q + 3, w * hv.w);
    }
}

__global__ __launch_bounds__(256) void k_div_elu(
    float* __restrict__ acc, const float* __restrict__ denom,
    const void* __restrict__ b1, const int* __restrict__ flags)
{
    const bool f32 = flags[0] & 1;
    const int t = blockIdx.x * 256 + threadIdx.x;
    if (t >= N_NODES * F_HID) return;
    const float v = acc[t] / denom[t >> 4] + loadf(b1, t & 15, f32);
    acc[t] = v > 0.f ? v : expm1f(v);
}

__global__ __launch_bounds__(256) void k_mid(
    const float* __restrict__ z,
    const void* __restrict__ W2, const void* __restrict__ a_s2,
    const void* __restrict__ a_d2, const int* __restrict__ flags,
    float* __restrict__ h2, float* __restrict__ asrc, float* __restrict__ adst)
{
    const bool f32 = flags[0] & 1;
    __shared__ float Wl[F_HID * F_HID];
    __shared__ float asl[F_HID];
    __shared__ float adl[F_HID];
    const int t = threadIdx.x;
    if (t < F_HID * F_HID) Wl[t] = loadf(W2, t, f32);
    if (t < F_HID) { asl[t] = loadf(a_s2, t, f32); adl[t] = loadf(a_d2, t, f32); }
    __syncthreads();
    const int node = blockIdx.x * 256 + t;
    if (node >= N_NODES) return;
    float zr[F_HID];
    const float4* zi = (const float4*)(z + (size_t)node * F_HID);
#pragma unroll
    for (int q = 0; q < 4; ++q) {
        const float4 zv = zi[q];
        zr[4*q+0]=zv.x; zr[4*q+1]=zv.y; zr[4*q+2]=zv.z; zr[4*q+3]=zv.w;
    }
    float h[F_HID];
#pragma unroll
    for (int k = 0; k < F_HID; ++k) h[k] = 0.f;
#pragma unroll
    for (int j = 0; j < F_HID; ++j) {
        const float zv = zr[j];
#pragma unroll
        for (int k = 0; k < F_HID; ++k) h[k] = fmaf(zv, Wl[j * F_HID + k], h[k]);
    }
    float s = 0.f, d = 0.f;
#pragma unroll
    for (int k = 0; k < F_HID; ++k) { s = fmaf(h[k], asl[k], s); d = fmaf(h[k], adl[k], d); }
    asrc[node] = s; adst[node] = d;
    float4* hb = (float4*)(h2 + (size_t)node * F_HID);
#pragma unroll
    for (int q = 0; q < 4; ++q)
        hb[q] = make_float4(h[4*q], h[4*q+1], h[4*q+2], h[4*q+3]);
}

__global__ __launch_bounds__(256) void k_out(
    const float* __restrict__ acc, const float* __restrict__ denom,
    const void* __restrict__ b2, const int* __restrict__ flags,
    float* __restrict__ out)
{
    const bool f32 = flags[0] & 1;
    const int t = blockIdx.x * 256 + threadIdx.x;
    if (t >= N_NODES * F_HID) return;
    out[t] = acc[t] / denom[t >> 4] + loadf(b2, t & 15, f32);
}

__global__ __launch_bounds__(256) void k_diag(float* __restrict__ out, float v)
{
    const int t = blockIdx.x * 256 + threadIdx.x;
    if (t < N_NODES * F_HID) out[t] = v;
}

extern "C" void kernel_launch(void* const* d_in, const int* in_sizes, int n_in,
                              void* d_out, int out_size, void* d_ws, size_t ws_size,
                              hipStream_t stream) {
    const void* x   = d_in[0];
    const void* ei  = d_in[1];
    const void* W1  = d_in[2];
    const void* a1s = d_in[3];
    const void* a1d = d_in[4];
    const void* b1  = d_in[5];
    const void* W2  = d_in[6];
    const void* a2s = d_in[7];
    const void* a2d = d_in[8];
    const void* b2  = d_in[9];
    float* out = (float*)d_out;

    float* ws = (float*)d_ws;
    int*      flags  = (int*)(ws + WS_FLAGS);
    float*    adst   = ws + WS_ADST;
    float*    adst2  = ws + WS_ADST2;
    int*      bcnt   = (int*)(ws + WS_BCNT);
    unsigned* hc1    = (unsigned*)(ws + WS_HC1);
    unsigned* hc2    = (unsigned*)(ws + WS_HC2);
    int*      bedges = (int*)(ws + WS_BEDGES);

    const dim3 blk(256);
    const dim3 grdN((N_NODES + 255) / 256);
    const dim3 grdE((N_EDGES + 255) / 256);
    const dim3 grdO((N_NODES * F_HID + 255) / 256);
    const dim3 grdBF(GRDB + GRDN_F);
    const dim3 grdB(NBUCK);

    if (ws_size >= WS_BUCKET_END * 4) {
        k_probe0 <<<dim3(1), blk, 0, stream>>>(x, ei, flags, bcnt);
        k_binfeat<<<grdBF, dim3(1024), 0, stream>>>(ei, x, W1, a1s, a1d, flags,
                                                    bcnt, bedges, hc1, adst);
        k_agg1   <<<grdB, dim3(512), 0, stream>>>(bcnt, bedges, adst, hc1,
                                                  b1, W2, a2s, a2d, flags, hc2, adst2);
        k_agg2   <<<grdB, dim3(512), 0, stream>>>(bcnt, bedges, adst2, hc2,
                                                  b2, flags, out);
    } else if (ws_size >= WS_ATOMIC_END * 4) {
        float* fb_h   = ws + WS_HC1;     // 1.6M fp32
        float* fb_acc = ws + WS_HC2;     // 1.6M fp32
        float* fb_den = ws + WS_FB_DEN;  // 100k
        float* fb_as  = ws + WS_FB_AS;   // 100k
        float* fb_ad  = ws + WS_ADST;
        k_probe0 <<<dim3(1), blk, 0, stream>>>(x, ei, flags, bcnt);
        k_feat1  <<<grdN, blk, 0, stream>>>(x, W1, a1s, a1d, flags, fb_h, fb_as, fb_ad);
        k_selfinit<<<grdO, blk, 0, stream>>>(fb_as, fb_ad, fb_h, fb_den, fb_acc);
        k_edge   <<<grdE, blk, 0, stream>>>(ei, flags, fb_as, fb_ad, fb_h, fb_den, fb_acc);
        k_div_elu<<<grdO, blk, 0, stream>>>(fb_acc, fb_den, b1, flags);
        k_mid    <<<grdN, blk, 0, stream>>>(fb_acc, W2, a2s, a2d, flags, fb_h, fb_as, fb_ad);
        k_selfinit<<<grdO, blk, 0, stream>>>(fb_as, fb_ad, fb_h, fb_den, fb_acc);
        k_edge   <<<grdE, blk, 0, stream>>>(ei, flags, fb_as, fb_ad, fb_h, fb_den, fb_acc);
        k_out    <<<grdO, blk, 0, stream>>>(fb_acc, fb_den, b2, flags, out);
    } else {
        k_diag<<<grdO, blk, 0, stream>>>(out, (float)(ws_size >> 10));
    }
}

// Round 3
// 234.119 us; speedup vs baseline: 3.7597x; 3.7597x over previous
//
#include <hip/hip_runtime.h>
#include <hip/hip_bf16.h>

typedef __hip_bfloat16 bf16;

static constexpr int N_NODES = 100000;
static constexpr int N_EDGES = 3200000;
static constexpr int F_IN    = 54;
static constexpr int F_HID   = 16;

// bucket path
static constexpr int BSHIFT    = 7;                  // 128 nodes per bucket
static constexpr int BNODES    = 128;
static constexpr int NBUCK     = (N_NODES + BNODES - 1) / BNODES;  // 782
static constexpr int CAP_B     = 5120;
static constexpr int BIN_CHUNK = 4096;               // was 8192; more blocks for overlap
static constexpr int BTHR      = 512;
static constexpr int GRDB      = (N_EDGES + BIN_CHUNK - 1) / BIN_CHUNK;  // 782
static constexpr int GRDN_F    = (N_NODES + BTHR - 1) / BTHR;            // 196
static constexpr int HELD      = CAP_B / 512;        // 10 register-held edges per thread

// ---------------------------------------------------------------------------
// ws layout (float indices) — offsets unchanged from the proven 258-us round.
// hc1/hc2: combined per-node 64-B rows, dword k = bf16(h[k]) | bf16(a_src)<<16
// srcs/rowbeg/rowcnt regions now unused (bsort fused into agg kernels).
// ---------------------------------------------------------------------------
static constexpr size_t WS_FLAGS  = 0;        // 4 ints
static constexpr size_t WS_ADST   = 4;        // 100000
static constexpr size_t WS_ADST2  = 100004;   // 100000
static constexpr size_t WS_BCNT   = 200004;   // 1024 ints
static constexpr size_t WS_HC1    = 401028;   // 1,600,000 dw
static constexpr size_t WS_HC2    = 2001028;  // 1,600,000 dw
static constexpr size_t WS_BEDGES = 3601028;  // NBUCK*CAP_B ints
static constexpr size_t WS_SRCS   = 7604868;  // (unused, kept for threshold)
static constexpr size_t WS_BUCKET_END = WS_SRCS + (size_t)NBUCK * CAP_B; // 11,608,708
static constexpr size_t WS_FB_DEN     = 3601028;
static constexpr size_t WS_FB_AS      = 3701028;
static constexpr size_t WS_ATOMIC_END = 3801028;

__device__ __forceinline__ float lrelu(float v) { return fmaxf(v, 0.2f * v); }
__device__ __forceinline__ float loadf(const void* p, int i, bool f32) {
    return f32 ? ((const float*)p)[i] : __bfloat162float(((const bf16*)p)[i]);
}
__device__ __forceinline__ unsigned f2bf(float f) {   // RNE fp32->bf16 bits
    unsigned u = __float_as_uint(f);
    return (u + 0x7FFFu + ((u >> 16) & 1u)) >> 16;
}

// ---------------------------------------------------------------------------
// Probe (+ zero bcnt): bit0 = floats fp32 ; bit1 = edge_index int64
// ---------------------------------------------------------------------------
__global__ __launch_bounds__(256) void k_probe0(
    const void* __restrict__ x, const void* __restrict__ ei,
    int* __restrict__ flags, int* __restrict__ bcnt)
{
    __shared__ int cnt, nz;
    const int t = threadIdx.x;
    if (t == 0) { cnt = 0; nz = 0; }
    __syncthreads();
    const unsigned u = ((const unsigned*)x)[t];
    if ((u & 0x7FFFu) >= 0x4800u) atomicAdd(&cnt, 1);
    if (t < 64) {
        if (((const unsigned*)ei)[2 * t + 1] != 0u) atomicAdd(&nz, 1);
    }
    for (int i = t; i < 1024; i += 256) bcnt[i] = 0;
    __syncthreads();
    if (t == 0) flags[0] = ((cnt >= 16) ? 1 : 0) | ((nz == 0) ? 2 : 0);
}

// ---------------------------------------------------------------------------
// k_binfeat (512 thr): [0,GRDB) bin w/ LDS edge cache; [GRDB,+GRDN_F) feat1:
// h1 = x@W1 (fp32 regs); emits combined row dword k = bf16(h[k])|bf16(a)<<16.
// ---------------------------------------------------------------------------
__global__ __launch_bounds__(512, 8) void k_binfeat(
    const void* __restrict__ ei, const void* __restrict__ x,
    const void* __restrict__ W1, const void* __restrict__ a_s,
    const void* __restrict__ a_d, const int* __restrict__ flags,
    int* __restrict__ bcnt, int* __restrict__ bedges,
    unsigned* __restrict__ hc, float* __restrict__ adst)
{
    __shared__ int            hist[NBUCK];
    __shared__ int            base[NBUCK];
    __shared__ int            cval[BIN_CHUNK];
    __shared__ unsigned short cbkt[BIN_CHUNK];
    __shared__ float Wl[F_IN * F_HID];
    __shared__ float asl[F_HID];
    __shared__ float adl[F_HID];
    const int t = threadIdx.x;
    const bool f32 = flags[0] & 1;
    const bool i64 = flags[0] & 2;

    if (blockIdx.x < GRDB) {
        const int e0 = blockIdx.x * BIN_CHUNK;
        const int valid = min(BIN_CHUNK, N_EDGES - e0);
        for (int i = t; i < NBUCK; i += BTHR) hist[i] = 0;
        __syncthreads();
#pragma unroll
        for (int i = 0; i < BIN_CHUNK / BTHR; ++i) {
            const int idx = i * BTHR + t;
            const int e = e0 + idx;
            if (idx < valid) {
                int s, d;
                if (i64) {
                    s = ((const int*)ei)[2 * (size_t)e];
                    d = ((const int*)ei)[2 * ((size_t)N_EDGES + e)];
                } else {
                    s = ((const int*)ei)[e];
                    d = ((const int*)ei)[(size_t)N_EDGES + e];
                }
                const int b = d >> BSHIFT;
                cval[idx] = (s << BSHIFT) | (d & (BNODES - 1));
                cbkt[idx] = (unsigned short)b;
                atomicAdd(&hist[b], 1);
            }
        }
        __syncthreads();
        for (int i = t; i < NBUCK; i += BTHR) {
            const int c = hist[i];
            base[i] = c ? atomicAdd(&bcnt[i], c) : 0;
            hist[i] = 0;
        }
        __syncthreads();
#pragma unroll
        for (int i = 0; i < BIN_CHUNK / BTHR; ++i) {
            const int idx = i * BTHR + t;
            if (idx < valid) {
                const int b = cbkt[idx];
                const int r = atomicAdd(&hist[b], 1);
                const int pos = base[b] + r;
                if (pos < CAP_B) bedges[(size_t)b * CAP_B + pos] = cval[idx];
            }
        }
    } else {
        for (int i = t; i < F_IN * F_HID; i += BTHR) Wl[i] = loadf(W1, i, f32);
        if (t < F_HID) { asl[t] = loadf(a_s, t, f32); adl[t] = loadf(a_d, t, f32); }
        __syncthreads();
        const int node = (blockIdx.x - GRDB) * BTHR + t;
        if (node >= N_NODES) return;

        float h[F_HID];
#pragma unroll
        for (int k = 0; k < F_HID; ++k) h[k] = 0.f;
        if (f32) {
            const float2* xp = (const float2*)((const float*)x + (size_t)node * F_IN);
#pragma unroll
            for (int j = 0; j < F_IN / 2; ++j) {
                const float2 v = xp[j];
#pragma unroll
                for (int k = 0; k < F_HID; ++k) {
                    h[k] = fmaf(v.x, Wl[(2*j)   * F_HID + k], h[k]);
                    h[k] = fmaf(v.y, Wl[(2*j+1) * F_HID + k], h[k]);
                }
            }
        } else {
            const unsigned* xu = (const unsigned*)x + (size_t)node * (F_IN / 2);
#pragma unroll
            for (int j = 0; j < F_IN / 2; ++j) {
                const unsigned u = xu[j];
                const float v0 = __uint_as_float(u << 16);
                const float v1 = __uint_as_float(u & 0xFFFF0000u);
#pragma unroll
                for (int k = 0; k < F_HID; ++k) {
                    h[k] = fmaf(v0, Wl[(2*j)   * F_HID + k], h[k]);
                    h[k] = fmaf(v1, Wl[(2*j+1) * F_HID + k], h[k]);
                }
            }
        }
        float s = 0.f, d = 0.f;
#pragma unroll
        for (int k = 0; k < F_HID; ++k) { s = fmaf(h[k], asl[k], s); d = fmaf(h[k], adl[k], d); }
        adst[node] = d;
        const unsigned ab = f2bf(s) << 16;
        unsigned pk[F_HID];
#pragma unroll
        for (int k = 0; k < F_HID; ++k) pk[k] = f2bf(h[k]) | ab;
        uint4* hb = (uint4*)(hc + (size_t)node * F_HID);
#pragma unroll
        for (int q = 0; q < 4; ++q)
            hb[q] = make_uint4(pk[4*q], pk[4*q+1], pk[4*q+2], pk[4*q+3]);
    }
}

// ---------------------------------------------------------------------------
// In-LDS bucket sort: register-held edges (static unroll -> no scratch),
// LDS hist + scan + scatter into srt[] (src indices, grouped by dst-local).
// Returns via LDS: hist[dl] = count, scanv[dl] = inclusive prefix.
// ---------------------------------------------------------------------------
__device__ __forceinline__ void bucket_sort_lds(
    const int* __restrict__ bedges, const int* __restrict__ bcnt, int b, int t,
    int* hist, int* scanv, int* cur, int* srt)
{
    if (t < BNODES) hist[t] = 0;
    __syncthreads();
    const int cnt = min(bcnt[b], CAP_B);
    const int* cv = bedges + (size_t)b * CAP_B;
    int held[HELD];
#pragma unroll
    for (int q = 0; q < HELD; ++q) {
        const int e = t + q * 512;                 // e <= 5119 < CAP_B: always in-bounds
        const int v = cv[e];
        held[q] = (e < cnt) ? v : -1;
    }
#pragma unroll
    for (int q = 0; q < HELD; ++q)
        if (held[q] >= 0) atomicAdd(&hist[held[q] & (BNODES - 1)], 1);
    __syncthreads();
    if (t < BNODES) scanv[t] = hist[t];
    __syncthreads();
#pragma unroll
    for (int off = 1; off < BNODES; off <<= 1) {
        const int v = (t < BNODES && t >= off) ? scanv[t - off] : 0;
        __syncthreads();
        if (t < BNODES) scanv[t] += v;
        __syncthreads();
    }
    if (t < BNODES) cur[t] = scanv[t] - hist[t];
    __syncthreads();
#pragma unroll
    for (int q = 0; q < HELD; ++q) {
        if (held[q] >= 0) {
            const int p  = held[q];
            const int r  = atomicAdd(&cur[p & (BNODES - 1)], 1);
            srt[r] = p >> BSHIFT;
        }
    }
    __syncthreads();
}

// ---------------------------------------------------------------------------
// k_agg1: one block per bucket. In-LDS sort (above) feeds the r1-proven
// register-accumulation gather loop: 16 lanes/node, one dword gather per edge,
// 8 independent gathers in flight. Epilogue fuses ELU + z@W2 (width-16
// shuffles) and emits the layer-2 combined row + adst2.
// ---------------------------------------------------------------------------
__global__ __launch_bounds__(512, 6) void k_agg1(
    const int* __restrict__ bcnt, const int* __restrict__ bedges,
    const float* __restrict__ adst, const unsigned* __restrict__ hc,
    const void* __restrict__ b1, const void* __restrict__ W2,
    const void* __restrict__ a_s2, const void* __restrict__ a_d2,
    const int* __restrict__ flags,
    unsigned* __restrict__ hc2, float* __restrict__ adst2)
{
    __shared__ float Wl[F_HID * F_HID];
    __shared__ float asl[F_HID], adl[F_HID], bl[F_HID];
    __shared__ float adL[BNODES];
    __shared__ int hist[BNODES], scanv[BNODES], cur[BNODES];
    __shared__ int srt[CAP_B];
    const bool f32 = flags[0] & 1;
    const int t = threadIdx.x;
    const int b = blockIdx.x;
    const int n0 = b << BSHIFT;
    if (t < F_HID * F_HID) Wl[t] = loadf(W2, t, f32);
    if (t < F_HID) {
        asl[t] = loadf(a_s2, t, f32);
        adl[t] = loadf(a_d2, t, f32);
        bl[t]  = loadf(b1, t, f32);
    }
    if (t < BNODES) {
        const int node = n0 + t;
        adL[t] = (node < N_NODES) ? adst[node] : 0.f;
    }
    bucket_sort_lds(bedges, bcnt, b, t, hist, scanv, cur, srt);

    const int k = t & 15;
    const int g = t >> 4;                           // 0..31
#pragma unroll
    for (int it = 0; it < 4; ++it) {
        const int dl = it * 32 + g;
        const int node = n0 + dl;
        if (node >= N_NODES) continue;              // group-uniform guard
        const float adn = adL[dl];
        const unsigned vs = hc[((size_t)node << 4) + k];
        const float w0 = __expf(lrelu(__uint_as_float(vs & 0xFFFF0000u) + adn));
        float denom = w0;
        float acc = w0 * __uint_as_float(vs << 16);
        const int n = hist[dl];
        const int* sp = srt + (scanv[dl] - n);
        int i = 0;
        for (; i + 8 <= n; i += 8) {
            const int s0 = sp[i+0], s1 = sp[i+1], s2 = sp[i+2], s3 = sp[i+3];
            const int s4 = sp[i+4], s5 = sp[i+5], s6 = sp[i+6], s7 = sp[i+7];
            const unsigned v0 = hc[((size_t)s0 << 4) + k];
            const unsigned v1 = hc[((size_t)s1 << 4) + k];
            const unsigned v2 = hc[((size_t)s2 << 4) + k];
            const unsigned v3 = hc[((size_t)s3 << 4) + k];
            const unsigned v4 = hc[((size_t)s4 << 4) + k];
            const unsigned v5 = hc[((size_t)s5 << 4) + k];
            const unsigned v6 = hc[((size_t)s6 << 4) + k];
            const unsigned v7 = hc[((size_t)s7 << 4) + k];
            const float e0 = __expf(lrelu(__uint_as_float(v0 & 0xFFFF0000u) + adn));
            const float e1 = __expf(lrelu(__uint_as_float(v1 & 0xFFFF0000u) + adn));
            const float e2 = __expf(lrelu(__uint_as_float(v2 & 0xFFFF0000u) + adn));
            const float e3 = __expf(lrelu(__uint_as_float(v3 & 0xFFFF0000u) + adn));
            const float e4 = __expf(lrelu(__uint_as_float(v4 & 0xFFFF0000u) + adn));
            const float e5 = __expf(lrelu(__uint_as_float(v5 & 0xFFFF0000u) + adn));
            const float e6 = __expf(lrelu(__uint_as_float(v6 & 0xFFFF0000u) + adn));
            const float e7 = __expf(lrelu(__uint_as_float(v7 & 0xFFFF0000u) + adn));
            denom += (e0 + e1 + e2 + e3) + (e4 + e5 + e6 + e7);
            acc = fmaf(e0, __uint_as_float(v0 << 16), acc);
            acc = fmaf(e1, __uint_as_float(v1 << 16), acc);
            acc = fmaf(e2, __uint_as_float(v2 << 16), acc);
            acc = fmaf(e3, __uint_as_float(v3 << 16), acc);
            acc = fmaf(e4, __uint_as_float(v4 << 16), acc);
            acc = fmaf(e5, __uint_as_float(v5 << 16), acc);
            acc = fmaf(e6, __uint_as_float(v6 << 16), acc);
            acc = fmaf(e7, __uint_as_float(v7 << 16), acc);
        }
        for (; i < n; ++i) {
            const unsigned v = hc[((size_t)sp[i] << 4) + k];
            const float w = __expf(lrelu(__uint_as_float(v & 0xFFFF0000u) + adn));
            denom += w;
            acc = fmaf(w, __uint_as_float(v << 16), acc);
        }
        float z = acc / denom + bl[k];
        z = z > 0.f ? z : expm1f(z);
        float hh = 0.f;
#pragma unroll
        for (int j = 0; j < F_HID; ++j) {
            const float zj = __shfl(z, j, 16);
            hh = fmaf(zj, Wl[j * F_HID + k], hh);
        }
        float s2 = hh * asl[k], d2 = hh * adl[k];
#pragma unroll
        for (int off = 1; off < 16; off <<= 1) {
            s2 += __shfl_xor(s2, off, 16);
            d2 += __shfl_xor(d2, off, 16);
        }
        hc2[((size_t)node << 4) + k] = f2bf(hh) | (f2bf(s2) << 16);
        if (k == 0) adst2[node] = d2;
    }
}

// ---------------------------------------------------------------------------
// k_agg2: same in-LDS sort (redundant, cheap) + gather on layer-2 rows;
// writes fp32 out.
// ---------------------------------------------------------------------------
__global__ __launch_bounds__(512, 6) void k_agg2(
    const int* __restrict__ bcnt, const int* __restrict__ bedges,
    const float* __restrict__ adst, const unsigned* __restrict__ hc,
    const void* __restrict__ b2, const int* __restrict__ flags,
    float* __restrict__ outp)
{
    __shared__ float bl[F_HID];
    __shared__ float adL[BNODES];
    __shared__ int hist[BNODES], scanv[BNODES], cur[BNODES];
    __shared__ int srt[CAP_B];
    const bool f32 = flags[0] & 1;
    const int t = threadIdx.x;
    const int b = blockIdx.x;
    const int n0 = b << BSHIFT;
    if (t < F_HID) bl[t] = loadf(b2, t, f32);
    if (t < BNODES) {
        const int node = n0 + t;
        adL[t] = (node < N_NODES) ? adst[node] : 0.f;
    }
    bucket_sort_lds(bedges, bcnt, b, t, hist, scanv, cur, srt);

    const int k = t & 15;
    const int g = t >> 4;
#pragma unroll
    for (int it = 0; it < 4; ++it) {
        const int dl = it * 32 + g;
        const int node = n0 + dl;
        if (node >= N_NODES) continue;
        const float adn = adL[dl];
        const unsigned vs = hc[((size_t)node << 4) + k];
        const float w0 = __expf(lrelu(__uint_as_float(vs & 0xFFFF0000u) + adn));
        float denom = w0;
        float acc = w0 * __uint_as_float(vs << 16);
        const int n = hist[dl];
        const int* sp = srt + (scanv[dl] - n);
        int i = 0;
        for (; i + 8 <= n; i += 8) {
            const int s0 = sp[i+0], s1 = sp[i+1], s2 = sp[i+2], s3 = sp[i+3];
            const int s4 = sp[i+4], s5 = sp[i+5], s6 = sp[i+6], s7 = sp[i+7];
            const unsigned v0 = hc[((size_t)s0 << 4) + k];
            const unsigned v1 = hc[((size_t)s1 << 4) + k];
            const unsigned v2 = hc[((size_t)s2 << 4) + k];
            const unsigned v3 = hc[((size_t)s3 << 4) + k];
            const unsigned v4 = hc[((size_t)s4 << 4) + k];
            const unsigned v5 = hc[((size_t)s5 << 4) + k];
            const unsigned v6 = hc[((size_t)s6 << 4) + k];
            const unsigned v7 = hc[((size_t)s7 << 4) + k];
            const float e0 = __expf(lrelu(__uint_as_float(v0 & 0xFFFF0000u) + adn));
            const float e1 = __expf(lrelu(__uint_as_float(v1 & 0xFFFF0000u) + adn));
            const float e2 = __expf(lrelu(__uint_as_float(v2 & 0xFFFF0000u) + adn));
            const float e3 = __expf(lrelu(__uint_as_float(v3 & 0xFFFF0000u) + adn));
            const float e4 = __expf(lrelu(__uint_as_float(v4 & 0xFFFF0000u) + adn));
            const float e5 = __expf(lrelu(__uint_as_float(v5 & 0xFFFF0000u) + adn));
            const float e6 = __expf(lrelu(__uint_as_float(v6 & 0xFFFF0000u) + adn));
            const float e7 = __expf(lrelu(__uint_as_float(v7 & 0xFFFF0000u) + adn));
            denom += (e0 + e1 + e2 + e3) + (e4 + e5 + e6 + e7);
            acc = fmaf(e0, __uint_as_float(v0 << 16), acc);
            acc = fmaf(e1, __uint_as_float(v1 << 16), acc);
            acc = fmaf(e2, __uint_as_float(v2 << 16), acc);
            acc = fmaf(e3, __uint_as_float(v3 << 16), acc);
            acc = fmaf(e4, __uint_as_float(v4 << 16), acc);
            acc = fmaf(e5, __uint_as_float(v5 << 16), acc);
            acc = fmaf(e6, __uint_as_float(v6 << 16), acc);
            acc = fmaf(e7, __uint_as_float(v7 << 16), acc);
        }
        for (; i < n; ++i) {
            const unsigned v = hc[((size_t)sp[i] << 4) + k];
            const float w = __expf(lrelu(__uint_as_float(v & 0xFFFF0000u) + adn));
            denom += w;
            acc = fmaf(w, __uint_as_float(v << 16), acc);
        }
        outp[((size_t)node << 4) + k] = acc / denom + bl[k];
    }
}

// ---------------------------------------------------------------------------
// Fallback kernels (round-3 proven atomic path, fp32 buffers) + diag
// ---------------------------------------------------------------------------
__global__ __launch_bounds__(256) void k_feat1(
    const void* __restrict__ x, const void* __restrict__ W1,
    const void* __restrict__ a_s, const void* __restrict__ a_d,
    const int* __restrict__ flags,
    float* __restrict__ hbuf, float* __restrict__ asrc, float* __restrict__ adst)
{
    const bool f32 = flags[0] & 1;
    __shared__ float Wl[F_IN * F_HID];
    __shared__ float asl[F_HID];
    __shared__ float adl[F_HID];
    const int t = threadIdx.x;
    for (int i = t; i < F_IN * F_HID; i += 256) Wl[i] = loadf(W1, i, f32);
    if (t < F_HID) { asl[t] = loadf(a_s, t, f32); adl[t] = loadf(a_d, t, f32); }
    __syncthreads();
    const int node = blockIdx.x * 256 + t;
    if (node >= N_NODES) return;
    float h[F_HID];
#pragma unroll
    for (int k = 0; k < F_HID; ++k) h[k] = 0.f;
    if (f32) {
        const float2* xp = (const float2*)((const float*)x + (size_t)node * F_IN);
#pragma unroll
        for (int j = 0; j < F_IN / 2; ++j) {
            const float2 v = xp[j];
#pragma unroll
            for (int k = 0; k < F_HID; ++k) {
                h[k] = fmaf(v.x, Wl[(2*j)   * F_HID + k], h[k]);
                h[k] = fmaf(v.y, Wl[(2*j+1) * F_HID + k], h[k]);
            }
        }
    } else {
        const unsigned* xu = (const unsigned*)x + (size_t)node * (F_IN / 2);
#pragma unroll
        for (int j = 0; j < F_IN / 2; ++j) {
            const unsigned u = xu[j];
            const float v0 = __uint_as_float(u << 16);
            const float v1 = __uint_as_float(u & 0xFFFF0000u);
#pragma unroll
            for (int k = 0; k < F_HID; ++k) {
                h[k] = fmaf(v0, Wl[(2*j)   * F_HID + k], h[k]);
                h[k] = fmaf(v1, Wl[(2*j+1) * F_HID + k], h[k]);
            }
        }
    }
    float s = 0.f, d = 0.f;
#pragma unroll
    for (int k = 0; k < F_HID; ++k) { s = fmaf(h[k], asl[k], s); d = fmaf(h[k], adl[k], d); }
    asrc[node] = s; adst[node] = d;
    float4* hb = (float4*)(hbuf + (size_t)node * F_HID);
#pragma unroll
    for (int q = 0; q < 4; ++q)
        hb[q] = make_float4(h[4*q], h[4*q+1], h[4*q+2], h[4*q+3]);
}

__global__ __launch_bounds__(256) void k_selfinit(
    const float* __restrict__ asrc, const float* __restrict__ adst,
    const float* __restrict__ h, float* __restrict__ denom, float* __restrict__ acc)
{
    const int t = blockIdx.x * 256 + threadIdx.x;
    if (t >= N_NODES * F_HID) return;
    const int n = t >> 4;
    const float w0 = __expf(lrelu(asrc[n] + adst[n]));
    if ((t & 15) == 0) denom[n] = w0;
    acc[t] = w0 * h[t];
}

__global__ __launch_bounds__(256) void k_edge(
    const void* __restrict__ ei, const int* __restrict__ flags,
    const float* __restrict__ asrc, const float* __restrict__ adst,
    const float* __restrict__ hbuf,
    float* __restrict__ denom, float* __restrict__ acc)
{
    const int e = blockIdx.x * 256 + threadIdx.x;
    if (e >= N_EDGES) return;
    int s, d;
    if (flags[0] & 2) {
        const long long* e64 = (const long long*)ei;
        s = (int)e64[e]; d = (int)e64[(size_t)N_EDGES + e];
    } else {
        const int* e32 = (const int*)ei;
        s = e32[e]; d = e32[(size_t)N_EDGES + e];
    }
    const float w = __expf(lrelu(asrc[s] + adst[d]));
    atomicAdd(&denom[d], w);
    const float4* hs = (const float4*)(hbuf + (size_t)s * F_HID);
    float* ad = acc + (size_t)d * F_HID;
#pragma unroll
    for (int q = 0; q < 4; ++q) {
        const float4 hv = hs[q];
        atomicAdd(ad + 4*q + 0, w * hv.x);
        atomicAdd(ad + 4*q + 1, w * hv.y);
        atomicAdd(ad + 4*q + 2, w * hv.z);
        atomicAdd(ad + 4*q + 3, w * hv.w);
    }
}

__global__ __launch_bounds__(256) void k_div_elu(
    float* __restrict__ acc, const float* __restrict__ denom,
    const void* __restrict__ b1, const int* __restrict__ flags)
{
    const bool f32 = flags[0] & 1;
    const int t = blockIdx.x * 256 + threadIdx.x;
    if (t >= N_NODES * F_HID) return;
    const float v = acc[t] / denom[t >> 4] + loadf(b1, t & 15, f32);
    acc[t] = v > 0.f ? v : expm1f(v);
}

__global__ __launch_bounds__(256) void k_mid(
    const float* __restrict__ z,
    const void* __restrict__ W2, const void* __restrict__ a_s2,
    const void* __restrict__ a_d2, const int* __restrict__ flags,
    float* __restrict__ h2, float* __restrict__ asrc, float* __restrict__ adst)
{
    const bool f32 = flags[0] & 1;
    __shared__ float Wl[F_HID * F_HID];
    __shared__ float asl[F_HID];
    __shared__ float adl[F_HID];
    const int t = threadIdx.x;
    if (t < F_HID * F_HID) Wl[t] = loadf(W2, t, f32);
    if (t < F_HID) { asl[t] = loadf(a_s2, t, f32); adl[t] = loadf(a_d2, t, f32); }
    __syncthreads();
    const int node = blockIdx.x * 256 + t;
    if (node >= N_NODES) return;
    float zr[F_HID];
    const float4* zi = (const float4*)(z + (size_t)node * F_HID);
#pragma unroll
    for (int q = 0; q < 4; ++q) {
        const float4 zv = zi[q];
        zr[4*q+0]=zv.x; zr[4*q+1]=zv.y; zr[4*q+2]=zv.z; zr[4*q+3]=zv.w;
    }
    float h[F_HID];
#pragma unroll
    for (int k = 0; k < F_HID; ++k) h[k] = 0.f;
#pragma unroll
    for (int j = 0; j < F_HID; ++j) {
        const float zv = zr[j];
#pragma unroll
        for (int k = 0; k < F_HID; ++k) h[k] = fmaf(zv, Wl[j * F_HID + k], h[k]);
    }
    float s = 0.f, d = 0.f;
#pragma unroll
    for (int k = 0; k < F_HID; ++k) { s = fmaf(h[k], asl[k], s); d = fmaf(h[k], adl[k], d); }
    asrc[node] = s; adst[node] = d;
    float4* hb = (float4*)(h2 + (size_t)node * F_HID);
#pragma unroll
    for (int q = 0; q < 4; ++q)
        hb[q] = make_float4(h[4*q], h[4*q+1], h[4*q+2], h[4*q+3]);
}

__global__ __launch_bounds__(256) void k_out(
    const float* __restrict__ acc, const float* __restrict__ denom,
    const void* __restrict__ b2, const int* __restrict__ flags,
    float* __restrict__ out)
{
    const bool f32 = flags[0] & 1;
    const int t = blockIdx.x * 256 + threadIdx.x;
    if (t >= N_NODES * F_HID) return;
    out[t] = acc[t] / denom[t >> 4] + loadf(b2, t & 15, f32);
}

__global__ __launch_bounds__(256) void k_diag(float* __restrict__ out, float v)
{
    const int t = blockIdx.x * 256 + threadIdx.x;
    if (t < N_NODES * F_HID) out[t] = v;
}

extern "C" void kernel_launch(void* const* d_in, const int* in_sizes, int n_in,
                              void* d_out, int out_size, void* d_ws, size_t ws_size,
                              hipStream_t stream) {
    const void* x   = d_in[0];
    const void* ei  = d_in[1];
    const void* W1  = d_in[2];
    const void* a1s = d_in[3];
    const void* a1d = d_in[4];
    const void* b1  = d_in[5];
    const void* W2  = d_in[6];
    const void* a2s = d_in[7];
    const void* a2d = d_in[8];
    const void* b2  = d_in[9];
    float* out = (float*)d_out;

    float* ws = (float*)d_ws;
    int*      flags  = (int*)(ws + WS_FLAGS);
    float*    adst   = ws + WS_ADST;
    float*    adst2  = ws + WS_ADST2;
    int*      bcnt   = (int*)(ws + WS_BCNT);
    unsigned* hc1    = (unsigned*)(ws + WS_HC1);
    unsigned* hc2    = (unsigned*)(ws + WS_HC2);
    int*      bedges = (int*)(ws + WS_BEDGES);

    const dim3 blk(256);
    const dim3 grdN((N_NODES + 255) / 256);
    const dim3 grdE((N_EDGES + 255) / 256);
    const dim3 grdO((N_NODES * F_HID + 255) / 256);
    const dim3 grdBF(GRDB + GRDN_F);
    const dim3 grdB(NBUCK);

    if (ws_size >= WS_BUCKET_END * 4) {
        k_probe0 <<<dim3(1), blk, 0, stream>>>(x, ei, flags, bcnt);
        k_binfeat<<<grdBF, dim3(BTHR), 0, stream>>>(ei, x, W1, a1s, a1d, flags,
                                                    bcnt, bedges, hc1, adst);
        k_agg1   <<<grdB, dim3(512), 0, stream>>>(bcnt, bedges, adst, hc1,
                                                  b1, W2, a2s, a2d, flags, hc2, adst2);
        k_agg2   <<<grdB, dim3(512), 0, stream>>>(bcnt, bedges, adst2, hc2,
                                                  b2, flags, out);
    } else if (ws_size >= WS_ATOMIC_END * 4) {
        float* fb_h   = ws + WS_HC1;     // 1.6M fp32
        float* fb_acc = ws + WS_HC2;     // 1.6M fp32
        float* fb_den = ws + WS_FB_DEN;  // 100k
        float* fb_as  = ws + WS_FB_AS;   // 100k
        float* fb_ad  = ws + WS_ADST;
        k_probe0 <<<dim3(1), blk, 0, stream>>>(x, ei, flags, bcnt);
        k_feat1  <<<grdN, blk, 0, stream>>>(x, W1, a1s, a1d, flags, fb_h, fb_as, fb_ad);
        k_selfinit<<<grdO, blk, 0, stream>>>(fb_as, fb_ad, fb_h, fb_den, fb_acc);
        k_edge   <<<grdE, blk, 0, stream>>>(ei, flags, fb_as, fb_ad, fb_h, fb_den, fb_acc);
        k_div_elu<<<grdO, blk, 0, stream>>>(fb_acc, fb_den, b1, flags);
        k_mid    <<<grdN, blk, 0, stream>>>(fb_acc, W2, a2s, a2d, flags, fb_h, fb_as, fb_ad);
        k_selfinit<<<grdO, blk, 0, stream>>>(fb_as, fb_ad, fb_h, fb_den, fb_acc);
        k_edge   <<<grdE, blk, 0, stream>>>(ei, flags, fb_as, fb_ad, fb_h, fb_den, fb_acc);
        k_out    <<<grdO, blk, 0, stream>>>(fb_acc, fb_den, b2, flags, out);
    } else {
        k_diag<<<grdO, blk, 0, stream>>>(out, (float)(ws_size >> 10));
    }
}

// Round 4
// 223.059 us; speedup vs baseline: 3.9461x; 1.0496x over previous
//
#include <hip/hip_runtime.h>
#include <hip/hip_bf16.h>

typedef __hip_bfloat16 bf16;

static constexpr int N_NODES = 100000;
static constexpr int N_EDGES = 3200000;
static constexpr int F_IN    = 54;
static constexpr int F_HID   = 16;

// bucket path
static constexpr int BSHIFT    = 7;                  // 128 nodes per bucket
static constexpr int BNODES    = 128;
static constexpr int NBUCK     = (N_NODES + BNODES - 1) / BNODES;  // 782
static constexpr int CAP_B     = 5120;
static constexpr int BIN_CHUNK = 4096;
static constexpr int BTHR      = 512;
static constexpr int GRDB      = (N_EDGES + BIN_CHUNK - 1) / BIN_CHUNK;  // 782
static constexpr int GRDN_F    = (N_NODES + BTHR - 1) / BTHR;            // 196
static constexpr int HELD      = CAP_B / 512;        // 10 register-held edges per thread

// ---------------------------------------------------------------------------
// ws layout (float indices). hc1/hc2 are now COMPACT 32-B rows:
// dword q = bf16(h[2q]) | bf16(h[2q+1])<<16  (8 dwords per node).
// a_src lives in separate fp32 tables (asrc1/asrc2) so the gather table fits
// the 4 MB per-XCD L2 (3.2 MB).
// ---------------------------------------------------------------------------
static constexpr size_t WS_FLAGS  = 0;        // 4 ints
static constexpr size_t WS_ADST   = 4;        // 100000
static constexpr size_t WS_ADST2  = 100004;   // 100000
static constexpr size_t WS_BCNT   = 200004;   // 1024 ints
static constexpr size_t WS_ASRC1  = 201028;   // 100000 (old rowbeg region)
static constexpr size_t WS_ASRC2  = 301028;   // 100000 (old rowcnt region)
static constexpr size_t WS_HC1    = 401028;   // 800,000 dw used (region 1.6M)
static constexpr size_t WS_HC2    = 2001028;  // 800,000 dw used (region 1.6M)
static constexpr size_t WS_BEDGES = 3601028;  // NBUCK*CAP_B ints
static constexpr size_t WS_SRCS   = 7604868;  // (unused, kept for threshold)
static constexpr size_t WS_BUCKET_END = WS_SRCS + (size_t)NBUCK * CAP_B; // 11,608,708
static constexpr size_t WS_FB_DEN     = 3601028;
static constexpr size_t WS_FB_AS      = 3701028;
static constexpr size_t WS_ATOMIC_END = 3801028;

__device__ __forceinline__ float lrelu(float v) { return fmaxf(v, 0.2f * v); }
__device__ __forceinline__ float loadf(const void* p, int i, bool f32) {
    return f32 ? ((const float*)p)[i] : __bfloat162float(((const bf16*)p)[i]);
}
__device__ __forceinline__ unsigned f2bf(float f) {   // RNE fp32->bf16 bits
    unsigned u = __float_as_uint(f);
    return (u + 0x7FFFu + ((u >> 16) & 1u)) >> 16;
}
__device__ __forceinline__ float bflo(unsigned u) { return __uint_as_float(u << 16); }
__device__ __forceinline__ float bfhi(unsigned u) { return __uint_as_float(u & 0xFFFF0000u); }

// ---------------------------------------------------------------------------
// Probe (+ zero bcnt): bit0 = floats fp32 ; bit1 = edge_index int64
// ---------------------------------------------------------------------------
__global__ __launch_bounds__(256) void k_probe0(
    const void* __restrict__ x, const void* __restrict__ ei,
    int* __restrict__ flags, int* __restrict__ bcnt)
{
    __shared__ int cnt, nz;
    const int t = threadIdx.x;
    if (t == 0) { cnt = 0; nz = 0; }
    __syncthreads();
    const unsigned u = ((const unsigned*)x)[t];
    if ((u & 0x7FFFu) >= 0x4800u) atomicAdd(&cnt, 1);
    if (t < 64) {
        if (((const unsigned*)ei)[2 * t + 1] != 0u) atomicAdd(&nz, 1);
    }
    for (int i = t; i < 1024; i += 256) bcnt[i] = 0;
    __syncthreads();
    if (t == 0) flags[0] = ((cnt >= 16) ? 1 : 0) | ((nz == 0) ? 2 : 0);
}

// ---------------------------------------------------------------------------
// k_binfeat (512 thr): [0,GRDB) bin w/ LDS edge cache; [GRDB,+GRDN_F) feat1:
// h1 = x@W1 (fp32 regs); emits compact 32-B row + fp32 asrc + fp32 adst.
// ---------------------------------------------------------------------------
__global__ __launch_bounds__(512, 8) void k_binfeat(
    const void* __restrict__ ei, const void* __restrict__ x,
    const void* __restrict__ W1, const void* __restrict__ a_s,
    const void* __restrict__ a_d, const int* __restrict__ flags,
    int* __restrict__ bcnt, int* __restrict__ bedges,
    unsigned* __restrict__ hc, float* __restrict__ asrc, float* __restrict__ adst)
{
    __shared__ int            hist[NBUCK];
    __shared__ int            base[NBUCK];
    __shared__ int            cval[BIN_CHUNK];
    __shared__ unsigned short cbkt[BIN_CHUNK];
    __shared__ float Wl[F_IN * F_HID];
    __shared__ float asl[F_HID];
    __shared__ float adl[F_HID];
    const int t = threadIdx.x;
    const bool f32 = flags[0] & 1;
    const bool i64 = flags[0] & 2;

    if (blockIdx.x < GRDB) {
        const int e0 = blockIdx.x * BIN_CHUNK;
        const int valid = min(BIN_CHUNK, N_EDGES - e0);
        for (int i = t; i < NBUCK; i += BTHR) hist[i] = 0;
        __syncthreads();
#pragma unroll
        for (int i = 0; i < BIN_CHUNK / BTHR; ++i) {
            const int idx = i * BTHR + t;
            const int e = e0 + idx;
            if (idx < valid) {
                int s, d;
                if (i64) {
                    s = ((const int*)ei)[2 * (size_t)e];
                    d = ((const int*)ei)[2 * ((size_t)N_EDGES + e)];
                } else {
                    s = ((const int*)ei)[e];
                    d = ((const int*)ei)[(size_t)N_EDGES + e];
                }
                const int b = d >> BSHIFT;
                cval[idx] = (s << BSHIFT) | (d & (BNODES - 1));
                cbkt[idx] = (unsigned short)b;
                atomicAdd(&hist[b], 1);
            }
        }
        __syncthreads();
        for (int i = t; i < NBUCK; i += BTHR) {
            const int c = hist[i];
            base[i] = c ? atomicAdd(&bcnt[i], c) : 0;
            hist[i] = 0;
        }
        __syncthreads();
#pragma unroll
        for (int i = 0; i < BIN_CHUNK / BTHR; ++i) {
            const int idx = i * BTHR + t;
            if (idx < valid) {
                const int b = cbkt[idx];
                const int r = atomicAdd(&hist[b], 1);
                const int pos = base[b] + r;
                if (pos < CAP_B) bedges[(size_t)b * CAP_B + pos] = cval[idx];
            }
        }
    } else {
        for (int i = t; i < F_IN * F_HID; i += BTHR) Wl[i] = loadf(W1, i, f32);
        if (t < F_HID) { asl[t] = loadf(a_s, t, f32); adl[t] = loadf(a_d, t, f32); }
        __syncthreads();
        const int node = (blockIdx.x - GRDB) * BTHR + t;
        if (node >= N_NODES) return;

        float h[F_HID];
#pragma unroll
        for (int k = 0; k < F_HID; ++k) h[k] = 0.f;
        if (f32) {
            const float2* xp = (const float2*)((const float*)x + (size_t)node * F_IN);
#pragma unroll
            for (int j = 0; j < F_IN / 2; ++j) {
                const float2 v = xp[j];
#pragma unroll
                for (int k = 0; k < F_HID; ++k) {
                    h[k] = fmaf(v.x, Wl[(2*j)   * F_HID + k], h[k]);
                    h[k] = fmaf(v.y, Wl[(2*j+1) * F_HID + k], h[k]);
                }
            }
        } else {
            const unsigned* xu = (const unsigned*)x + (size_t)node * (F_IN / 2);
#pragma unroll
            for (int j = 0; j < F_IN / 2; ++j) {
                const unsigned u = xu[j];
                const float v0 = __uint_as_float(u << 16);
                const float v1 = __uint_as_float(u & 0xFFFF0000u);
#pragma unroll
                for (int k = 0; k < F_HID; ++k) {
                    h[k] = fmaf(v0, Wl[(2*j)   * F_HID + k], h[k]);
                    h[k] = fmaf(v1, Wl[(2*j+1) * F_HID + k], h[k]);
                }
            }
        }
        float s = 0.f, d = 0.f;
#pragma unroll
        for (int k = 0; k < F_HID; ++k) { s = fmaf(h[k], asl[k], s); d = fmaf(h[k], adl[k], d); }
        asrc[node] = s;
        adst[node] = d;
        unsigned pk[8];
#pragma unroll
        for (int q = 0; q < 8; ++q) pk[q] = f2bf(h[2*q]) | (f2bf(h[2*q+1]) << 16);
        uint4* hb = (uint4*)(hc + ((size_t)node << 3));
        hb[0] = make_uint4(pk[0], pk[1], pk[2], pk[3]);
        hb[1] = make_uint4(pk[4], pk[5], pk[6], pk[7]);
    }
}

// ---------------------------------------------------------------------------
// In-LDS bucket sort (proven r3): register-held edges, LDS hist+scan+scatter.
// ---------------------------------------------------------------------------
__device__ __forceinline__ void bucket_sort_lds(
    const int* __restrict__ bedges, const int* __restrict__ bcnt, int b, int t,
    int* hist, int* scanv, int* cur, int* srt)
{
    if (t < BNODES) hist[t] = 0;
    __syncthreads();
    const int cnt = min(bcnt[b], CAP_B);
    const int* cv = bedges + (size_t)b * CAP_B;
    int held[HELD];
#pragma unroll
    for (int q = 0; q < HELD; ++q) {
        const int e = t + q * 512;                 // e <= 5119 < CAP_B: in-bounds
        const int v = cv[e];
        held[q] = (e < cnt) ? v : -1;
    }
#pragma unroll
    for (int q = 0; q < HELD; ++q)
        if (held[q] >= 0) atomicAdd(&hist[held[q] & (BNODES - 1)], 1);
    __syncthreads();
    if (t < BNODES) scanv[t] = hist[t];
    __syncthreads();
#pragma unroll
    for (int off = 1; off < BNODES; off <<= 1) {
        const int v = (t < BNODES && t >= off) ? scanv[t - off] : 0;
        __syncthreads();
        if (t < BNODES) scanv[t] += v;
        __syncthreads();
    }
    if (t < BNODES) cur[t] = scanv[t] - hist[t];
    __syncthreads();
#pragma unroll
    for (int q = 0; q < HELD; ++q) {
        if (held[q] >= 0) {
            const int p  = held[q];
            const int r  = atomicAdd(&cur[p & (BNODES - 1)], 1);
            srt[r] = p >> BSHIFT;
        }
    }
    __syncthreads();
}

// ---------------------------------------------------------------------------
// k_agg1: one block per bucket, 4 lanes per node (512 thr = 128 groups).
// In-LDS sort feeds register-accumulation: per edge, lane loads uint2 (4 h
// comps) from the 3.2 MB compact table (L2-resident) + fp32 asrc (400 KB,
// hot). 8 edges in flight. Epilogue fuses ELU + z@W2 (width-4 shuffles) and
// emits layer-2 compact row + asrc2 + adst2.
// ---------------------------------------------------------------------------
__global__ __launch_bounds__(512, 6) void k_agg1(
    const int* __restrict__ bcnt, const int* __restrict__ bedges,
    const float* __restrict__ asrc, const float* __restrict__ adst,
    const unsigned* __restrict__ hc,
    const void* __restrict__ b1, const void* __restrict__ W2,
    const void* __restrict__ a_s2, const void* __restrict__ a_d2,
    const int* __restrict__ flags,
    unsigned* __restrict__ hc2, float* __restrict__ asrc2, float* __restrict__ adst2)
{
    __shared__ float Wl[F_HID * F_HID];
    __shared__ float asl[F_HID], adl[F_HID], bl[F_HID];
    __shared__ float adL[BNODES], asL[BNODES];
    __shared__ int hist[BNODES], scanv[BNODES], cur[BNODES];
    __shared__ int srt[CAP_B];
    const bool f32 = flags[0] & 1;
    const int t = threadIdx.x;
    const int b = blockIdx.x;
    const int n0 = b << BSHIFT;
    if (t < F_HID * F_HID) Wl[t] = loadf(W2, t, f32);
    if (t < F_HID) {
        asl[t] = loadf(a_s2, t, f32);
        adl[t] = loadf(a_d2, t, f32);
        bl[t]  = loadf(b1, t, f32);
    }
    if (t < BNODES) {
        const int node = n0 + t;
        const bool ok = node < N_NODES;
        adL[t] = ok ? adst[node] : 0.f;
        asL[t] = ok ? asrc[node] : 0.f;
    }
    bucket_sort_lds(bedges, bcnt, b, t, hist, scanv, cur, srt);

    const int k2 = t & 3;                 // lane in group: h comps 4*k2..4*k2+3
    const int g  = t >> 2;                // node-local 0..127
    const int node = n0 + g;
    if (node < N_NODES) {                 // group-uniform
        const int K = k2 << 2;
        const float adn = adL[g];
        // self-loop init
        const uint2 us = *(const uint2*)(hc + ((size_t)node << 3) + (k2 << 1));
        const float w0 = __expf(lrelu(asL[g] + adn));
        float denom = w0;
        float a0 = w0 * bflo(us.x), a1 = w0 * bfhi(us.x);
        float a2 = w0 * bflo(us.y), a3 = w0 * bfhi(us.y);
        const int n = hist[g];
        const int* sp = srt + (scanv[g] - n);
        int i = 0;
        for (; i + 8 <= n; i += 8) {
            const int s0 = sp[i+0], s1 = sp[i+1], s2_ = sp[i+2], s3 = sp[i+3];
            const int s4 = sp[i+4], s5 = sp[i+5], s6 = sp[i+6], s7 = sp[i+7];
            const uint2 v0 = *(const uint2*)(hc + ((size_t)s0 << 3) + (k2 << 1));
            const uint2 v1 = *(const uint2*)(hc + ((size_t)s1 << 3) + (k2 << 1));
            const uint2 v2 = *(const uint2*)(hc + ((size_t)s2_ << 3) + (k2 << 1));
            const uint2 v3 = *(const uint2*)(hc + ((size_t)s3 << 3) + (k2 << 1));
            const uint2 v4 = *(const uint2*)(hc + ((size_t)s4 << 3) + (k2 << 1));
            const uint2 v5 = *(const uint2*)(hc + ((size_t)s5 << 3) + (k2 << 1));
            const uint2 v6 = *(const uint2*)(hc + ((size_t)s6 << 3) + (k2 << 1));
            const uint2 v7 = *(const uint2*)(hc + ((size_t)s7 << 3) + (k2 << 1));
            const float x0 = asrc[s0], x1 = asrc[s1], x2 = asrc[s2_], x3 = asrc[s3];
            const float x4 = asrc[s4], x5 = asrc[s5], x6 = asrc[s6], x7 = asrc[s7];
            const float e0 = __expf(lrelu(x0 + adn));
            const float e1 = __expf(lrelu(x1 + adn));
            const float e2 = __expf(lrelu(x2 + adn));
            const float e3 = __expf(lrelu(x3 + adn));
            const float e4 = __expf(lrelu(x4 + adn));
            const float e5 = __expf(lrelu(x5 + adn));
            const float e6 = __expf(lrelu(x6 + adn));
            const float e7 = __expf(lrelu(x7 + adn));
            denom += (e0 + e1 + e2 + e3) + (e4 + e5 + e6 + e7);
            a0 = fmaf(e0, bflo(v0.x), a0); a1 = fmaf(e0, bfhi(v0.x), a1);
            a2 = fmaf(e0, bflo(v0.y), a2); a3 = fmaf(e0, bfhi(v0.y), a3);
            a0 = fmaf(e1, bflo(v1.x), a0); a1 = fmaf(e1, bfhi(v1.x), a1);
            a2 = fmaf(e1, bflo(v1.y), a2); a3 = fmaf(e1, bfhi(v1.y), a3);
            a0 = fmaf(e2, bflo(v2.x), a0); a1 = fmaf(e2, bfhi(v2.x), a1);
            a2 = fmaf(e2, bflo(v2.y), a2); a3 = fmaf(e2, bfhi(v2.y), a3);
            a0 = fmaf(e3, bflo(v3.x), a0); a1 = fmaf(e3, bfhi(v3.x), a1);
            a2 = fmaf(e3, bflo(v3.y), a2); a3 = fmaf(e3, bfhi(v3.y), a3);
            a0 = fmaf(e4, bflo(v4.x), a0); a1 = fmaf(e4, bfhi(v4.x), a1);
            a2 = fmaf(e4, bflo(v4.y), a2); a3 = fmaf(e4, bfhi(v4.y), a3);
            a0 = fmaf(e5, bflo(v5.x), a0); a1 = fmaf(e5, bfhi(v5.x), a1);
            a2 = fmaf(e5, bflo(v5.y), a2); a3 = fmaf(e5, bfhi(v5.y), a3);
            a0 = fmaf(e6, bflo(v6.x), a0); a1 = fmaf(e6, bfhi(v6.x), a1);
            a2 = fmaf(e6, bflo(v6.y), a2); a3 = fmaf(e6, bfhi(v6.y), a3);
            a0 = fmaf(e7, bflo(v7.x), a0); a1 = fmaf(e7, bfhi(v7.x), a1);
            a2 = fmaf(e7, bflo(v7.y), a2); a3 = fmaf(e7, bfhi(v7.y), a3);
        }
        for (; i < n; ++i) {
            const int s = sp[i];
            const uint2 v = *(const uint2*)(hc + ((size_t)s << 3) + (k2 << 1));
            const float w = __expf(lrelu(asrc[s] + adn));
            denom += w;
            a0 = fmaf(w, bflo(v.x), a0); a1 = fmaf(w, bfhi(v.x), a1);
            a2 = fmaf(w, bflo(v.y), a2); a3 = fmaf(w, bfhi(v.y), a3);
        }
        // epilogue: divide + bias + ELU
        const float inv = 1.f / denom;
        float z0 = a0 * inv + bl[K+0];
        float z1 = a1 * inv + bl[K+1];
        float z2 = a2 * inv + bl[K+2];
        float z3 = a3 * inv + bl[K+3];
        z0 = z0 > 0.f ? z0 : expm1f(z0);
        z1 = z1 > 0.f ? z1 : expm1f(z1);
        z2 = z2 > 0.f ? z2 : expm1f(z2);
        z3 = z3 > 0.f ? z3 : expm1f(z3);
        // z @ W2 via width-4 shuffles (each lane produces h2[K..K+3])
        float hh0 = 0.f, hh1 = 0.f, hh2 = 0.f, hh3 = 0.f;
#pragma unroll
        for (int jl = 0; jl < 4; ++jl) {
            const float zj0 = __shfl(z0, jl, 4);
            const float zj1 = __shfl(z1, jl, 4);
            const float zj2 = __shfl(z2, jl, 4);
            const float zj3 = __shfl(z3, jl, 4);
            const int jb = jl << 2;
            hh0 = fmaf(zj0, Wl[(jb+0)*F_HID + K+0], hh0);
            hh1 = fmaf(zj0, Wl[(jb+0)*F_HID + K+1], hh1);
            hh2 = fmaf(zj0, Wl[(jb+0)*F_HID + K+2], hh2);
            hh3 = fmaf(zj0, Wl[(jb+0)*F_HID + K+3], hh3);
            hh0 = fmaf(zj1, Wl[(jb+1)*F_HID + K+0], hh0);
            hh1 = fmaf(zj1, Wl[(jb+1)*F_HID + K+1], hh1);
            hh2 = fmaf(zj1, Wl[(jb+1)*F_HID + K+2], hh2);
            hh3 = fmaf(zj1, Wl[(jb+1)*F_HID + K+3], hh3);
            hh0 = fmaf(zj2, Wl[(jb+2)*F_HID + K+0], hh0);
            hh1 = fmaf(zj2, Wl[(jb+2)*F_HID + K+1], hh1);
            hh2 = fmaf(zj2, Wl[(jb+2)*F_HID + K+2], hh2);
            hh3 = fmaf(zj2, Wl[(jb+2)*F_HID + K+3], hh3);
            hh0 = fmaf(zj3, Wl[(jb+3)*F_HID + K+0], hh0);
            hh1 = fmaf(zj3, Wl[(jb+3)*F_HID + K+1], hh1);
            hh2 = fmaf(zj3, Wl[(jb+3)*F_HID + K+2], hh2);
            hh3 = fmaf(zj3, Wl[(jb+3)*F_HID + K+3], hh3);
        }
        float s2 = hh0*asl[K+0] + hh1*asl[K+1] + hh2*asl[K+2] + hh3*asl[K+3];
        float d2 = hh0*adl[K+0] + hh1*adl[K+1] + hh2*adl[K+2] + hh3*adl[K+3];
        s2 += __shfl_xor(s2, 1, 4); s2 += __shfl_xor(s2, 2, 4);
        d2 += __shfl_xor(d2, 1, 4); d2 += __shfl_xor(d2, 2, 4);
        uint2 w;
        w.x = f2bf(hh0) | (f2bf(hh1) << 16);
        w.y = f2bf(hh2) | (f2bf(hh3) << 16);
        *(uint2*)(hc2 + ((size_t)node << 3) + (k2 << 1)) = w;
        if (k2 == 0) { asrc2[node] = s2; adst2[node] = d2; }
    }
}

// ---------------------------------------------------------------------------
// k_agg2: same structure on layer-2 rows; writes fp32 out (float4 per lane).
// ---------------------------------------------------------------------------
__global__ __launch_bounds__(512, 6) void k_agg2(
    const int* __restrict__ bcnt, const int* __restrict__ bedges,
    const float* __restrict__ asrc, const float* __restrict__ adst,
    const unsigned* __restrict__ hc,
    const void* __restrict__ b2, const int* __restrict__ flags,
    float* __restrict__ outp)
{
    __shared__ float bl[F_HID];
    __shared__ float adL[BNODES], asL[BNODES];
    __shared__ int hist[BNODES], scanv[BNODES], cur[BNODES];
    __shared__ int srt[CAP_B];
    const bool f32 = flags[0] & 1;
    const int t = threadIdx.x;
    const int b = blockIdx.x;
    const int n0 = b << BSHIFT;
    if (t < F_HID) bl[t] = loadf(b2, t, f32);
    if (t < BNODES) {
        const int node = n0 + t;
        const bool ok = node < N_NODES;
        adL[t] = ok ? adst[node] : 0.f;
        asL[t] = ok ? asrc[node] : 0.f;
    }
    bucket_sort_lds(bedges, bcnt, b, t, hist, scanv, cur, srt);

    const int k2 = t & 3;
    const int g  = t >> 2;
    const int node = n0 + g;
    if (node < N_NODES) {
        const int K = k2 << 2;
        const float adn = adL[g];
        const uint2 us = *(const uint2*)(hc + ((size_t)node << 3) + (k2 << 1));
        const float w0 = __expf(lrelu(asL[g] + adn));
        float denom = w0;
        float a0 = w0 * bflo(us.x), a1 = w0 * bfhi(us.x);
        float a2 = w0 * bflo(us.y), a3 = w0 * bfhi(us.y);
        const int n = hist[g];
        const int* sp = srt + (scanv[g] - n);
        int i = 0;
        for (; i + 8 <= n; i += 8) {
            const int s0 = sp[i+0], s1 = sp[i+1], s2_ = sp[i+2], s3 = sp[i+3];
            const int s4 = sp[i+4], s5 = sp[i+5], s6 = sp[i+6], s7 = sp[i+7];
            const uint2 v0 = *(const uint2*)(hc + ((size_t)s0 << 3) + (k2 << 1));
            const uint2 v1 = *(const uint2*)(hc + ((size_t)s1 << 3) + (k2 << 1));
            const uint2 v2 = *(const uint2*)(hc + ((size_t)s2_ << 3) + (k2 << 1));
            const uint2 v3 = *(const uint2*)(hc + ((size_t)s3 << 3) + (k2 << 1));
            const uint2 v4 = *(const uint2*)(hc + ((size_t)s4 << 3) + (k2 << 1));
            const uint2 v5 = *(const uint2*)(hc + ((size_t)s5 << 3) + (k2 << 1));
            const uint2 v6 = *(const uint2*)(hc + ((size_t)s6 << 3) + (k2 << 1));
            const uint2 v7 = *(const uint2*)(hc + ((size_t)s7 << 3) + (k2 << 1));
            const float x0 = asrc[s0], x1 = asrc[s1], x2 = asrc[s2_], x3 = asrc[s3];
            const float x4 = asrc[s4], x5 = asrc[s5], x6 = asrc[s6], x7 = asrc[s7];
            const float e0 = __expf(lrelu(x0 + adn));
            const float e1 = __expf(lrelu(x1 + adn));
            const float e2 = __expf(lrelu(x2 + adn));
            const float e3 = __expf(lrelu(x3 + adn));
            const float e4 = __expf(lrelu(x4 + adn));
            const float e5 = __expf(lrelu(x5 + adn));
            const float e6 = __expf(lrelu(x6 + adn));
            const float e7 = __expf(lrelu(x7 + adn));
            denom += (e0 + e1 + e2 + e3) + (e4 + e5 + e6 + e7);
            a0 = fmaf(e0, bflo(v0.x), a0); a1 = fmaf(e0, bfhi(v0.x), a1);
            a2 = fmaf(e0, bflo(v0.y), a2); a3 = fmaf(e0, bfhi(v0.y), a3);
            a0 = fmaf(e1, bflo(v1.x), a0); a1 = fmaf(e1, bfhi(v1.x), a1);
            a2 = fmaf(e1, bflo(v1.y), a2); a3 = fmaf(e1, bfhi(v1.y), a3);
            a0 = fmaf(e2, bflo(v2.x), a0); a1 = fmaf(e2, bfhi(v2.x), a1);
            a2 = fmaf(e2, bflo(v2.y), a2); a3 = fmaf(e2, bfhi(v2.y), a3);
            a0 = fmaf(e3, bflo(v3.x), a0); a1 = fmaf(e3, bfhi(v3.x), a1);
            a2 = fmaf(e3, bflo(v3.y), a2); a3 = fmaf(e3, bfhi(v3.y), a3);
            a0 = fmaf(e4, bflo(v4.x), a0); a1 = fmaf(e4, bfhi(v4.x), a1);
            a2 = fmaf(e4, bflo(v4.y), a2); a3 = fmaf(e4, bfhi(v4.y), a3);
            a0 = fmaf(e5, bflo(v5.x), a0); a1 = fmaf(e5, bfhi(v5.x), a1);
            a2 = fmaf(e5, bflo(v5.y), a2); a3 = fmaf(e5, bfhi(v5.y), a3);
            a0 = fmaf(e6, bflo(v6.x), a0); a1 = fmaf(e6, bfhi(v6.x), a1);
            a2 = fmaf(e6, bflo(v6.y), a2); a3 = fmaf(e6, bfhi(v6.y), a3);
            a0 = fmaf(e7, bflo(v7.x), a0); a1 = fmaf(e7, bfhi(v7.x), a1);
            a2 = fmaf(e7, bflo(v7.y), a2); a3 = fmaf(e7, bfhi(v7.y), a3);
        }
        for (; i < n; ++i) {
            const int s = sp[i];
            const uint2 v = *(const uint2*)(hc + ((size_t)s << 3) + (k2 << 1));
            const float w = __expf(lrelu(asrc[s] + adn));
            denom += w;
            a0 = fmaf(w, bflo(v.x), a0); a1 = fmaf(w, bfhi(v.x), a1);
            a2 = fmaf(w, bflo(v.y), a2); a3 = fmaf(w, bfhi(v.y), a3);
        }
        const float inv = 1.f / denom;
        float4 o;
        o.x = a0 * inv + bl[K+0];
        o.y = a1 * inv + bl[K+1];
        o.z = a2 * inv + bl[K+2];
        o.w = a3 * inv + bl[K+3];
        *(float4*)(outp + ((size_t)node << 4) + K) = o;
    }
}

// ---------------------------------------------------------------------------
// Fallback kernels (round-3 proven atomic path, fp32 buffers) + diag
// ---------------------------------------------------------------------------
__global__ __launch_bounds__(256) void k_feat1(
    const void* __restrict__ x, const void* __restrict__ W1,
    const void* __restrict__ a_s, const void* __restrict__ a_d,
    const int* __restrict__ flags,
    float* __restrict__ hbuf, float* __restrict__ asrc, float* __restrict__ adst)
{
    const bool f32 = flags[0] & 1;
    __shared__ float Wl[F_IN * F_HID];
    __shared__ float asl[F_HID];
    __shared__ float adl[F_HID];
    const int t = threadIdx.x;
    for (int i = t; i < F_IN * F_HID; i += 256) Wl[i] = loadf(W1, i, f32);
    if (t < F_HID) { asl[t] = loadf(a_s, t, f32); adl[t] = loadf(a_d, t, f32); }
    __syncthreads();
    const int node = blockIdx.x * 256 + t;
    if (node >= N_NODES) return;
    float h[F_HID];
#pragma unroll
    for (int k = 0; k < F_HID; ++k) h[k] = 0.f;
    if (f32) {
        const float2* xp = (const float2*)((const float*)x + (size_t)node * F_IN);
#pragma unroll
        for (int j = 0; j < F_IN / 2; ++j) {
            const float2 v = xp[j];
#pragma unroll
            for (int k = 0; k < F_HID; ++k) {
                h[k] = fmaf(v.x, Wl[(2*j)   * F_HID + k], h[k]);
                h[k] = fmaf(v.y, Wl[(2*j+1) * F_HID + k], h[k]);
            }
        }
    } else {
        const unsigned* xu = (const unsigned*)x + (size_t)node * (F_IN / 2);
#pragma unroll
        for (int j = 0; j < F_IN / 2; ++j) {
            const unsigned u = xu[j];
            const float v0 = __uint_as_float(u << 16);
            const float v1 = __uint_as_float(u & 0xFFFF0000u);
#pragma unroll
            for (int k = 0; k < F_HID; ++k) {
                h[k] = fmaf(v0, Wl[(2*j)   * F_HID + k], h[k]);
                h[k] = fmaf(v1, Wl[(2*j+1) * F_HID + k], h[k]);
            }
        }
    }
    float s = 0.f, d = 0.f;
#pragma unroll
    for (int k = 0; k < F_HID; ++k) { s = fmaf(h[k], asl[k], s); d = fmaf(h[k], adl[k], d); }
    asrc[node] = s; adst[node] = d;
    float4* hb = (float4*)(hbuf + (size_t)node * F_HID);
#pragma unroll
    for (int q = 0; q < 4; ++q)
        hb[q] = make_float4(h[4*q], h[4*q+1], h[4*q+2], h[4*q+3]);
}

__global__ __launch_bounds__(256) void k_selfinit(
    const float* __restrict__ asrc, const float* __restrict__ adst,
    const float* __restrict__ h, float* __restrict__ denom, float* __restrict__ acc)
{
    const int t = blockIdx.x * 256 + threadIdx.x;
    if (t >= N_NODES * F_HID) return;
    const int n = t >> 4;
    const float w0 = __expf(lrelu(asrc[n] + adst[n]));
    if ((t & 15) == 0) denom[n] = w0;
    acc[t] = w0 * h[t];
}

__global__ __launch_bounds__(256) void k_edge(
    const void* __restrict__ ei, const int* __restrict__ flags,
    const float* __restrict__ asrc, const float* __restrict__ adst,
    const float* __restrict__ hbuf,
    float* __restrict__ denom, float* __restrict__ acc)
{
    const int e = blockIdx.x * 256 + threadIdx.x;
    if (e >= N_EDGES) return;
    int s, d;
    if (flags[0] & 2) {
        const long long* e64 = (const long long*)ei;
        s = (int)e64[e]; d = (int)e64[(size_t)N_EDGES + e];
    } else {
        const int* e32 = (const int*)ei;
        s = e32[e]; d = e32[(size_t)N_EDGES + e];
    }
    const float w = __expf(lrelu(asrc[s] + adst[d]));
    atomicAdd(&denom[d], w);
    const float4* hs = (const float4*)(hbuf + (size_t)s * F_HID);
    float* ad = acc + (size_t)d * F_HID;
#pragma unroll
    for (int q = 0; q < 4; ++q) {
        const float4 hv = hs[q];
        atomicAdd(ad + 4*q + 0, w * hv.x);
        atomicAdd(ad + 4*q + 1, w * hv.y);
        atomicAdd(ad + 4*q + 2, w * hv.z);
        atomicAdd(ad + 4*q + 3, w * hv.w);
    }
}

__global__ __launch_bounds__(256) void k_div_elu(
    float* __restrict__ acc, const float* __restrict__ denom,
    const void* __restrict__ b1, const int* __restrict__ flags)
{
    const bool f32 = flags[0] & 1;
    const int t = blockIdx.x * 256 + threadIdx.x;
    if (t >= N_NODES * F_HID) return;
    const float v = acc[t] / denom[t >> 4] + loadf(b1, t & 15, f32);
    acc[t] = v > 0.f ? v : expm1f(v);
}

__global__ __launch_bounds__(256) void k_mid(
    const float* __restrict__ z,
    const void* __restrict__ W2, const void* __restrict__ a_s2,
    const void* __restrict__ a_d2, const int* __restrict__ flags,
    float* __restrict__ h2, float* __restrict__ asrc, float* __restrict__ adst)
{
    const bool f32 = flags[0] & 1;
    __shared__ float Wl[F_HID * F_HID];
    __shared__ float asl[F_HID];
    __shared__ float adl[F_HID];
    const int t = threadIdx.x;
    if (t < F_HID * F_HID) Wl[t] = loadf(W2, t, f32);
    if (t < F_HID) { asl[t] = loadf(a_s2, t, f32); adl[t] = loadf(a_d2, t, f32); }
    __syncthreads();
    const int node = blockIdx.x * 256 + t;
    if (node >= N_NODES) return;
    float zr[F_HID];
    const float4* zi = (const float4*)(z + (size_t)node * F_HID);
#pragma unroll
    for (int q = 0; q < 4; ++q) {
        const float4 zv = zi[q];
        zr[4*q+0]=zv.x; zr[4*q+1]=zv.y; zr[4*q+2]=zv.z; zr[4*q+3]=zv.w;
    }
    float h[F_HID];
#pragma unroll
    for (int k = 0; k < F_HID; ++k) h[k] = 0.f;
#pragma unroll
    for (int j = 0; j < F_HID; ++j) {
        const float zv = zr[j];
#pragma unroll
        for (int k = 0; k < F_HID; ++k) h[k] = fmaf(zv, Wl[j * F_HID + k], h[k]);
    }
    float s = 0.f, d = 0.f;
#pragma unroll
    for (int k = 0; k < F_HID; ++k) { s = fmaf(h[k], asl[k], s); d = fmaf(h[k], adl[k], d); }
    asrc[node] = s; adst[node] = d;
    float4* hb = (float4*)(h2 + (size_t)node * F_HID);
#pragma unroll
    for (int q = 0; q < 4; ++q)
        hb[q] = make_float4(h[4*q], h[4*q+1], h[4*q+2], h[4*q+3]);
}

__global__ __launch_bounds__(256) void k_out(
    const float* __restrict__ acc, const float* __restrict__ denom,
    const void* __restrict__ b2, const int* __restrict__ flags,
    float* __restrict__ out)
{
    const bool f32 = flags[0] & 1;
    const int t = blockIdx.x * 256 + threadIdx.x;
    if (t >= N_NODES * F_HID) return;
    out[t] = acc[t] / denom[t >> 4] + loadf(b2, t & 15, f32);
}

__global__ __launch_bounds__(256) void k_diag(float* __restrict__ out, float v)
{
    const int t = blockIdx.x * 256 + threadIdx.x;
    if (t < N_NODES * F_HID) out[t] = v;
}

extern "C" void kernel_launch(void* const* d_in, const int* in_sizes, int n_in,
                              void* d_out, int out_size, void* d_ws, size_t ws_size,
                              hipStream_t stream) {
    const void* x   = d_in[0];
    const void* ei  = d_in[1];
    const void* W1  = d_in[2];
    const void* a1s = d_in[3];
    const void* a1d = d_in[4];
    const void* b1  = d_in[5];
    const void* W2  = d_in[6];
    const void* a2s = d_in[7];
    const void* a2d = d_in[8];
    const void* b2  = d_in[9];
    float* out = (float*)d_out;

    float* ws = (float*)d_ws;
    int*      flags  = (int*)(ws + WS_FLAGS);
    float*    adst   = ws + WS_ADST;
    float*    adst2  = ws + WS_ADST2;
    int*      bcnt   = (int*)(ws + WS_BCNT);
    float*    asrc1  = ws + WS_ASRC1;
    float*    asrc2  = ws + WS_ASRC2;
    unsigned* hc1    = (unsigned*)(ws + WS_HC1);
    unsigned* hc2    = (unsigned*)(ws + WS_HC2);
    int*      bedges = (int*)(ws + WS_BEDGES);

    const dim3 blk(256);
    const dim3 grdN((N_NODES + 255) / 256);
    const dim3 grdE((N_EDGES + 255) / 256);
    const dim3 grdO((N_NODES * F_HID + 255) / 256);
    const dim3 grdBF(GRDB + GRDN_F);
    const dim3 grdB(NBUCK);

    if (ws_size >= WS_BUCKET_END * 4) {
        k_probe0 <<<dim3(1), blk, 0, stream>>>(x, ei, flags, bcnt);
        k_binfeat<<<grdBF, dim3(BTHR), 0, stream>>>(ei, x, W1, a1s, a1d, flags,
                                                    bcnt, bedges, hc1, asrc1, adst);
        k_agg1   <<<grdB, dim3(512), 0, stream>>>(bcnt, bedges, asrc1, adst, hc1,
                                                  b1, W2, a2s, a2d, flags,
                                                  hc2, asrc2, adst2);
        k_agg2   <<<grdB, dim3(512), 0, stream>>>(bcnt, bedges, asrc2, adst2, hc2,
                                                  b2, flags, out);
    } else if (ws_size >= WS_ATOMIC_END * 4) {
        float* fb_h   = ws + WS_HC1;     // 1.6M fp32
        float* fb_acc = ws + WS_HC2;     // 1.6M fp32
        float* fb_den = ws + WS_FB_DEN;  // 100k
        float* fb_as  = ws + WS_FB_AS;   // 100k
        float* fb_ad  = ws + WS_ADST;
        k_probe0 <<<dim3(1), blk, 0, stream>>>(x, ei, flags, bcnt);
        k_feat1  <<<grdN, blk, 0, stream>>>(x, W1, a1s, a1d, flags, fb_h, fb_as, fb_ad);
        k_selfinit<<<grdO, blk, 0, stream>>>(fb_as, fb_ad, fb_h, fb_den, fb_acc);
        k_edge   <<<grdE, blk, 0, stream>>>(ei, flags, fb_as, fb_ad, fb_h, fb_den, fb_acc);
        k_div_elu<<<grdO, blk, 0, stream>>>(fb_acc, fb_den, b1, flags);
        k_mid    <<<grdN, blk, 0, stream>>>(fb_acc, W2, a2s, a2d, flags, fb_h, fb_as, fb_ad);
        k_selfinit<<<grdO, blk, 0, stream>>>(fb_as, fb_ad, fb_h, fb_den, fb_acc);
        k_edge   <<<grdE, blk, 0, stream>>>(ei, flags, fb_as, fb_ad, fb_h, fb_den, fb_acc);
        k_out    <<<grdO, blk, 0, stream>>>(fb_acc, fb_den, b2, flags, out);
    } else {
        k_diag<<<grdO, blk, 0, stream>>>(out, (float)(ws_size >> 10));
    }
}

// Round 5
// 221.970 us; speedup vs baseline: 3.9654x; 1.0049x over previous
//
#include <hip/hip_runtime.h>
#include <hip/hip_bf16.h>

typedef __hip_bfloat16 bf16;

static constexpr int N_NODES = 100000;
static constexpr int N_EDGES = 3200000;
static constexpr int F_IN    = 54;
static constexpr int F_HID   = 16;

// bucket path
static constexpr int BSHIFT    = 7;                  // 128 nodes per bucket
static constexpr int BNODES    = 128;
static constexpr int NBUCK     = (N_NODES + BNODES - 1) / BNODES;  // 782
static constexpr int CAP_B     = 5120;
static constexpr int BIN_CHUNK = 4096;
static constexpr int BTHR      = 512;
static constexpr int EPT       = BIN_CHUNK / BTHR;   // 8 register-held edges
static constexpr int GRDB      = (N_EDGES + BIN_CHUNK - 1) / BIN_CHUNK;  // 782
static constexpr int GRDN_F    = (N_NODES + BTHR - 1) / BTHR;            // 196
static constexpr int HELD      = CAP_B / 512;        // 10 register-held edges per thread

// ---------------------------------------------------------------------------
// ws layout (float indices). hc1/hc2 are COMPACT 32-B rows:
// dword q = bf16(h[2q]) | bf16(h[2q+1])<<16  (8 dwords per node).
// a_src lives in separate fp32 tables (asrc1/asrc2) so the gather table fits
// the 4 MB per-XCD L2 (3.2 MB).
// ---------------------------------------------------------------------------
static constexpr size_t WS_FLAGS  = 0;        // 4 ints
static constexpr size_t WS_ADST   = 4;        // 100000
static constexpr size_t WS_ADST2  = 100004;   // 100000
static constexpr size_t WS_BCNT   = 200004;   // 1024 ints
static constexpr size_t WS_ASRC1  = 201028;   // 100000
static constexpr size_t WS_ASRC2  = 301028;   // 100000
static constexpr size_t WS_HC1    = 401028;   // 800,000 dw used (region 1.6M)
static constexpr size_t WS_HC2    = 2001028;  // 800,000 dw used (region 1.6M)
static constexpr size_t WS_BEDGES = 3601028;  // NBUCK*CAP_B ints
static constexpr size_t WS_SRCS   = 7604868;  // (unused, kept for threshold)
static constexpr size_t WS_BUCKET_END = WS_SRCS + (size_t)NBUCK * CAP_B; // 11,608,708
static constexpr size_t WS_FB_DEN     = 3601028;
static constexpr size_t WS_FB_AS      = 3701028;
static constexpr size_t WS_ATOMIC_END = 3801028;

__device__ __forceinline__ float lrelu(float v) { return fmaxf(v, 0.2f * v); }
__device__ __forceinline__ float loadf(const void* p, int i, bool f32) {
    return f32 ? ((const float*)p)[i] : __bfloat162float(((const bf16*)p)[i]);
}
__device__ __forceinline__ unsigned f2bf(float f) {   // RNE fp32->bf16 bits
    unsigned u = __float_as_uint(f);
    return (u + 0x7FFFu + ((u >> 16) & 1u)) >> 16;
}
__device__ __forceinline__ float bflo(unsigned u) { return __uint_as_float(u << 16); }
__device__ __forceinline__ float bfhi(unsigned u) { return __uint_as_float(u & 0xFFFF0000u); }

// ---------------------------------------------------------------------------
// Probe (+ zero bcnt): bit0 = floats fp32 ; bit1 = edge_index int64
// ---------------------------------------------------------------------------
__global__ __launch_bounds__(256) void k_probe0(
    const void* __restrict__ x, const void* __restrict__ ei,
    int* __restrict__ flags, int* __restrict__ bcnt)
{
    __shared__ int cnt, nz;
    const int t = threadIdx.x;
    if (t == 0) { cnt = 0; nz = 0; }
    __syncthreads();
    const unsigned u = ((const unsigned*)x)[t];
    if ((u & 0x7FFFu) >= 0x4800u) atomicAdd(&cnt, 1);
    if (t < 64) {
        if (((const unsigned*)ei)[2 * t + 1] != 0u) atomicAdd(&nz, 1);
    }
    for (int i = t; i < 1024; i += 256) bcnt[i] = 0;
    __syncthreads();
    if (t == 0) flags[0] = ((cnt >= 16) ? 1 : 0) | ((nz == 0) ? 2 : 0);
}

// ---------------------------------------------------------------------------
// k_binfeat (512 thr): [0,GRDB) bin with REGISTER-held edges (no LDS edge
// cache -> ~10 KB LDS -> 4 blocks/CU, latency hiding); [GRDB,+GRDN_F) feat1:
// h1 = x@W1 (fp32 regs); emits compact 32-B row + fp32 asrc + fp32 adst.
// ---------------------------------------------------------------------------
__global__ __launch_bounds__(512, 8) void k_binfeat(
    const void* __restrict__ ei, const void* __restrict__ x,
    const void* __restrict__ W1, const void* __restrict__ a_s,
    const void* __restrict__ a_d, const int* __restrict__ flags,
    int* __restrict__ bcnt, int* __restrict__ bedges,
    unsigned* __restrict__ hc, float* __restrict__ asrc, float* __restrict__ adst)
{
    __shared__ int   hist[NBUCK];
    __shared__ int   base[NBUCK];
    __shared__ float Wl[F_IN * F_HID];
    __shared__ float asl[F_HID];
    __shared__ float adl[F_HID];
    const int t = threadIdx.x;
    const bool f32 = flags[0] & 1;
    const bool i64 = flags[0] & 2;

    if (blockIdx.x < GRDB) {
        const int e0 = blockIdx.x * BIN_CHUNK;
        const int valid = min(BIN_CHUNK, N_EDGES - e0);
        for (int i = t; i < NBUCK; i += BTHR) hist[i] = 0;
        __syncthreads();
        int cval_r[EPT];
        int bkt_r[EPT];
#pragma unroll
        for (int q = 0; q < EPT; ++q) {
            const int idx = q * BTHR + t;
            const int e = e0 + idx;
            bkt_r[q] = -1;
            if (idx < valid) {
                int s, d;
                if (i64) {
                    s = ((const int*)ei)[2 * (size_t)e];
                    d = ((const int*)ei)[2 * ((size_t)N_EDGES + e)];
                } else {
                    s = ((const int*)ei)[e];
                    d = ((const int*)ei)[(size_t)N_EDGES + e];
                }
                bkt_r[q] = d >> BSHIFT;
                cval_r[q] = (s << BSHIFT) | (d & (BNODES - 1));
                atomicAdd(&hist[bkt_r[q]], 1);
            }
        }
        __syncthreads();
        for (int i = t; i < NBUCK; i += BTHR) {
            const int c = hist[i];
            base[i] = c ? atomicAdd(&bcnt[i], c) : 0;
            hist[i] = 0;
        }
        __syncthreads();
#pragma unroll
        for (int q = 0; q < EPT; ++q) {
            if (bkt_r[q] >= 0) {
                const int b = bkt_r[q];
                const int r = atomicAdd(&hist[b], 1);
                const int pos = base[b] + r;
                if (pos < CAP_B) bedges[(size_t)b * CAP_B + pos] = cval_r[q];
            }
        }
    } else {
        for (int i = t; i < F_IN * F_HID; i += BTHR) Wl[i] = loadf(W1, i, f32);
        if (t < F_HID) { asl[t] = loadf(a_s, t, f32); adl[t] = loadf(a_d, t, f32); }
        __syncthreads();
        const int node = (blockIdx.x - GRDB) * BTHR + t;
        if (node >= N_NODES) return;

        float h[F_HID];
#pragma unroll
        for (int k = 0; k < F_HID; ++k) h[k] = 0.f;
        if (f32) {
            const float2* xp = (const float2*)((const float*)x + (size_t)node * F_IN);
#pragma unroll
            for (int j = 0; j < F_IN / 2; ++j) {
                const float2 v = xp[j];
#pragma unroll
                for (int k = 0; k < F_HID; ++k) {
                    h[k] = fmaf(v.x, Wl[(2*j)   * F_HID + k], h[k]);
                    h[k] = fmaf(v.y, Wl[(2*j+1) * F_HID + k], h[k]);
                }
            }
        } else {
            const unsigned* xu = (const unsigned*)x + (size_t)node * (F_IN / 2);
#pragma unroll
            for (int j = 0; j < F_IN / 2; ++j) {
                const unsigned u = xu[j];
                const float v0 = __uint_as_float(u << 16);
                const float v1 = __uint_as_float(u & 0xFFFF0000u);
#pragma unroll
                for (int k = 0; k < F_HID; ++k) {
                    h[k] = fmaf(v0, Wl[(2*j)   * F_HID + k], h[k]);
                    h[k] = fmaf(v1, Wl[(2*j+1) * F_HID + k], h[k]);
                }
            }
        }
        float s = 0.f, d = 0.f;
#pragma unroll
        for (int k = 0; k < F_HID; ++k) { s = fmaf(h[k], asl[k], s); d = fmaf(h[k], adl[k], d); }
        asrc[node] = s;
        adst[node] = d;
        unsigned pk[8];
#pragma unroll
        for (int q = 0; q < 8; ++q) pk[q] = f2bf(h[2*q]) | (f2bf(h[2*q+1]) << 16);
        uint4* hb = (uint4*)(hc + ((size_t)node << 3));
        hb[0] = make_uint4(pk[0], pk[1], pk[2], pk[3]);
        hb[1] = make_uint4(pk[4], pk[5], pk[6], pk[7]);
    }
}

// ---------------------------------------------------------------------------
// In-LDS bucket sort (proven r3): register-held edges, LDS hist+scan+scatter.
// ---------------------------------------------------------------------------
__device__ __forceinline__ void bucket_sort_lds(
    const int* __restrict__ bedges, const int* __restrict__ bcnt, int b, int t,
    int* hist, int* scanv, int* cur, int* srt)
{
    if (t < BNODES) hist[t] = 0;
    __syncthreads();
    const int cnt = min(bcnt[b], CAP_B);
    const int* cv = bedges + (size_t)b * CAP_B;
    int held[HELD];
#pragma unroll
    for (int q = 0; q < HELD; ++q) {
        const int e = t + q * 512;                 // e <= 5119 < CAP_B: in-bounds
        const int v = cv[e];
        held[q] = (e < cnt) ? v : -1;
    }
#pragma unroll
    for (int q = 0; q < HELD; ++q)
        if (held[q] >= 0) atomicAdd(&hist[held[q] & (BNODES - 1)], 1);
    __syncthreads();
    if (t < BNODES) scanv[t] = hist[t];
    __syncthreads();
#pragma unroll
    for (int off = 1; off < BNODES; off <<= 1) {
        const int v = (t < BNODES && t >= off) ? scanv[t - off] : 0;
        __syncthreads();
        if (t < BNODES) scanv[t] += v;
        __syncthreads();
    }
    if (t < BNODES) cur[t] = scanv[t] - hist[t];
    __syncthreads();
#pragma unroll
    for (int q = 0; q < HELD; ++q) {
        if (held[q] >= 0) {
            const int p  = held[q];
            const int r  = atomicAdd(&cur[p & (BNODES - 1)], 1);
            srt[r] = p >> BSHIFT;
        }
    }
    __syncthreads();
}

// ---------------------------------------------------------------------------
// k_agg1: one block per bucket, 4 lanes per node (512 thr = 128 groups).
// In-LDS sort feeds register-accumulation: per edge, lane loads uint2 (4 h
// comps) from the 3.2 MB compact table (L2-resident) + fp32 asrc (400 KB,
// hot). 8 edges in flight. Epilogue fuses ELU + z@W2 (width-4 shuffles) and
// emits layer-2 compact row + asrc2 + adst2.
// ---------------------------------------------------------------------------
__global__ __launch_bounds__(512, 6) void k_agg1(
    const int* __restrict__ bcnt, const int* __restrict__ bedges,
    const float* __restrict__ asrc, const float* __restrict__ adst,
    const unsigned* __restrict__ hc,
    const void* __restrict__ b1, const void* __restrict__ W2,
    const void* __restrict__ a_s2, const void* __restrict__ a_d2,
    const int* __restrict__ flags,
    unsigned* __restrict__ hc2, float* __restrict__ asrc2, float* __restrict__ adst2)
{
    __shared__ float Wl[F_HID * F_HID];
    __shared__ float asl[F_HID], adl[F_HID], bl[F_HID];
    __shared__ float adL[BNODES], asL[BNODES];
    __shared__ int hist[BNODES], scanv[BNODES], cur[BNODES];
    __shared__ int srt[CAP_B];
    const bool f32 = flags[0] & 1;
    const int t = threadIdx.x;
    const int b = blockIdx.x;
    const int n0 = b << BSHIFT;
    if (t < F_HID * F_HID) Wl[t] = loadf(W2, t, f32);
    if (t < F_HID) {
        asl[t] = loadf(a_s2, t, f32);
        adl[t] = loadf(a_d2, t, f32);
        bl[t]  = loadf(b1, t, f32);
    }
    if (t < BNODES) {
        const int node = n0 + t;
        const bool ok = node < N_NODES;
        adL[t] = ok ? adst[node] : 0.f;
        asL[t] = ok ? asrc[node] : 0.f;
    }
    bucket_sort_lds(bedges, bcnt, b, t, hist, scanv, cur, srt);

    const int k2 = t & 3;                 // lane in group: h comps 4*k2..4*k2+3
    const int g  = t >> 2;                // node-local 0..127
    const int node = n0 + g;
    if (node < N_NODES) {                 // group-uniform
        const int K = k2 << 2;
        const float adn = adL[g];
        // self-loop init
        const uint2 us = *(const uint2*)(hc + ((size_t)node << 3) + (k2 << 1));
        const float w0 = __expf(lrelu(asL[g] + adn));
        float denom = w0;
        float a0 = w0 * bflo(us.x), a1 = w0 * bfhi(us.x);
        float a2 = w0 * bflo(us.y), a3 = w0 * bfhi(us.y);
        const int n = hist[g];
        const int* sp = srt + (scanv[g] - n);
        int i = 0;
        for (; i + 8 <= n; i += 8) {
            const int s0 = sp[i+0], s1 = sp[i+1], s2_ = sp[i+2], s3 = sp[i+3];
            const int s4 = sp[i+4], s5 = sp[i+5], s6 = sp[i+6], s7 = sp[i+7];
            const uint2 v0 = *(const uint2*)(hc + ((size_t)s0 << 3) + (k2 << 1));
            const uint2 v1 = *(const uint2*)(hc + ((size_t)s1 << 3) + (k2 << 1));
            const uint2 v2 = *(const uint2*)(hc + ((size_t)s2_ << 3) + (k2 << 1));
            const uint2 v3 = *(const uint2*)(hc + ((size_t)s3 << 3) + (k2 << 1));
            const uint2 v4 = *(const uint2*)(hc + ((size_t)s4 << 3) + (k2 << 1));
            const uint2 v5 = *(const uint2*)(hc + ((size_t)s5 << 3) + (k2 << 1));
            const uint2 v6 = *(const uint2*)(hc + ((size_t)s6 << 3) + (k2 << 1));
            const uint2 v7 = *(const uint2*)(hc + ((size_t)s7 << 3) + (k2 << 1));
            const float x0 = asrc[s0], x1 = asrc[s1], x2 = asrc[s2_], x3 = asrc[s3];
            const float x4 = asrc[s4], x5 = asrc[s5], x6 = asrc[s6], x7 = asrc[s7];
            const float e0 = __expf(lrelu(x0 + adn));
            const float e1 = __expf(lrelu(x1 + adn));
            const float e2 = __expf(lrelu(x2 + adn));
            const float e3 = __expf(lrelu(x3 + adn));
            const float e4 = __expf(lrelu(x4 + adn));
            const float e5 = __expf(lrelu(x5 + adn));
            const float e6 = __expf(lrelu(x6 + adn));
            const float e7 = __expf(lrelu(x7 + adn));
            denom += (e0 + e1 + e2 + e3) + (e4 + e5 + e6 + e7);
            a0 = fmaf(e0, bflo(v0.x), a0); a1 = fmaf(e0, bfhi(v0.x), a1);
            a2 = fmaf(e0, bflo(v0.y), a2); a3 = fmaf(e0, bfhi(v0.y), a3);
            a0 = fmaf(e1, bflo(v1.x), a0); a1 = fmaf(e1, bfhi(v1.x), a1);
            a2 = fmaf(e1, bflo(v1.y), a2); a3 = fmaf(e1, bfhi(v1.y), a3);
            a0 = fmaf(e2, bflo(v2.x), a0); a1 = fmaf(e2, bfhi(v2.x), a1);
            a2 = fmaf(e2, bflo(v2.y), a2); a3 = fmaf(e2, bfhi(v2.y), a3);
            a0 = fmaf(e3, bflo(v3.x), a0); a1 = fmaf(e3, bfhi(v3.x), a1);
            a2 = fmaf(e3, bflo(v3.y), a2); a3 = fmaf(e3, bfhi(v3.y), a3);
            a0 = fmaf(e4, bflo(v4.x), a0); a1 = fmaf(e4, bfhi(v4.x), a1);
            a2 = fmaf(e4, bflo(v4.y), a2); a3 = fmaf(e4, bfhi(v4.y), a3);
            a0 = fmaf(e5, bflo(v5.x), a0); a1 = fmaf(e5, bfhi(v5.x), a1);
            a2 = fmaf(e5, bflo(v5.y), a2); a3 = fmaf(e5, bfhi(v5.y), a3);
            a0 = fmaf(e6, bflo(v6.x), a0); a1 = fmaf(e6, bfhi(v6.x), a1);
            a2 = fmaf(e6, bflo(v6.y), a2); a3 = fmaf(e6, bfhi(v6.y), a3);
            a0 = fmaf(e7, bflo(v7.x), a0); a1 = fmaf(e7, bfhi(v7.x), a1);
            a2 = fmaf(e7, bflo(v7.y), a2); a3 = fmaf(e7, bfhi(v7.y), a3);
        }
        for (; i < n; ++i) {
            const int s = sp[i];
            const uint2 v = *(const uint2*)(hc + ((size_t)s << 3) + (k2 << 1));
            const float w = __expf(lrelu(asrc[s] + adn));
            denom += w;
            a0 = fmaf(w, bflo(v.x), a0); a1 = fmaf(w, bfhi(v.x), a1);
            a2 = fmaf(w, bflo(v.y), a2); a3 = fmaf(w, bfhi(v.y), a3);
        }
        // epilogue: divide + bias + ELU
        const float inv = 1.f / denom;
        float z0 = a0 * inv + bl[K+0];
        float z1 = a1 * inv + bl[K+1];
        float z2 = a2 * inv + bl[K+2];
        float z3 = a3 * inv + bl[K+3];
        z0 = z0 > 0.f ? z0 : expm1f(z0);
        z1 = z1 > 0.f ? z1 : expm1f(z1);
        z2 = z2 > 0.f ? z2 : expm1f(z2);
        z3 = z3 > 0.f ? z3 : expm1f(z3);
        // z @ W2 via width-4 shuffles (each lane produces h2[K..K+3])
        float hh0 = 0.f, hh1 = 0.f, hh2 = 0.f, hh3 = 0.f;
#pragma unroll
        for (int jl = 0; jl < 4; ++jl) {
            const float zj0 = __shfl(z0, jl, 4);
            const float zj1 = __shfl(z1, jl, 4);
            const float zj2 = __shfl(z2, jl, 4);
            const float zj3 = __shfl(z3, jl, 4);
            const int jb = jl << 2;
            hh0 = fmaf(zj0, Wl[(jb+0)*F_HID + K+0], hh0);
            hh1 = fmaf(zj0, Wl[(jb+0)*F_HID + K+1], hh1);
            hh2 = fmaf(zj0, Wl[(jb+0)*F_HID + K+2], hh2);
            hh3 = fmaf(zj0, Wl[(jb+0)*F_HID + K+3], hh3);
            hh0 = fmaf(zj1, Wl[(jb+1)*F_HID + K+0], hh0);
            hh1 = fmaf(zj1, Wl[(jb+1)*F_HID + K+1], hh1);
            hh2 = fmaf(zj1, Wl[(jb+1)*F_HID + K+2], hh2);
            hh3 = fmaf(zj1, Wl[(jb+1)*F_HID + K+3], hh3);
            hh0 = fmaf(zj2, Wl[(jb+2)*F_HID + K+0], hh0);
            hh1 = fmaf(zj2, Wl[(jb+2)*F_HID + K+1], hh1);
            hh2 = fmaf(zj2, Wl[(jb+2)*F_HID + K+2], hh2);
            hh3 = fmaf(zj2, Wl[(jb+2)*F_HID + K+3], hh3);
            hh0 = fmaf(zj3, Wl[(jb+3)*F_HID + K+0], hh0);
            hh1 = fmaf(zj3, Wl[(jb+3)*F_HID + K+1], hh1);
            hh2 = fmaf(zj3, Wl[(jb+3)*F_HID + K+2], hh2);
            hh3 = fmaf(zj3, Wl[(jb+3)*F_HID + K+3], hh3);
        }
        float s2 = hh0*asl[K+0] + hh1*asl[K+1] + hh2*asl[K+2] + hh3*asl[K+3];
        float d2 = hh0*adl[K+0] + hh1*adl[K+1] + hh2*adl[K+2] + hh3*adl[K+3];
        s2 += __shfl_xor(s2, 1, 4); s2 += __shfl_xor(s2, 2, 4);
        d2 += __shfl_xor(d2, 1, 4); d2 += __shfl_xor(d2, 2, 4);
        uint2 w;
        w.x = f2bf(hh0) | (f2bf(hh1) << 16);
        w.y = f2bf(hh2) | (f2bf(hh3) << 16);
        *(uint2*)(hc2 + ((size_t)node << 3) + (k2 << 1)) = w;
        if (k2 == 0) { asrc2[node] = s2; adst2[node] = d2; }
    }
}

// ---------------------------------------------------------------------------
// k_agg2: same structure on layer-2 rows; writes fp32 out (float4 per lane).
// ---------------------------------------------------------------------------
__global__ __launch_bounds__(512, 6) void k_agg2(
    const int* __restrict__ bcnt, const int* __restrict__ bedges,
    const float* __restrict__ asrc, const float* __restrict__ adst,
    const unsigned* __restrict__ hc,
    const void* __restrict__ b2, const int* __restrict__ flags,
    float* __restrict__ outp)
{
    __shared__ float bl[F_HID];
    __shared__ float adL[BNODES], asL[BNODES];
    __shared__ int hist[BNODES], scanv[BNODES], cur[BNODES];
    __shared__ int srt[CAP_B];
    const bool f32 = flags[0] & 1;
    const int t = threadIdx.x;
    const int b = blockIdx.x;
    const int n0 = b << BSHIFT;
    if (t < F_HID) bl[t] = loadf(b2, t, f32);
    if (t < BNODES) {
        const int node = n0 + t;
        const bool ok = node < N_NODES;
        adL[t] = ok ? adst[node] : 0.f;
        asL[t] = ok ? asrc[node] : 0.f;
    }
    bucket_sort_lds(bedges, bcnt, b, t, hist, scanv, cur, srt);

    const int k2 = t & 3;
    const int g  = t >> 2;
    const int node = n0 + g;
    if (node < N_NODES) {
        const int K = k2 << 2;
        const float adn = adL[g];
        const uint2 us = *(const uint2*)(hc + ((size_t)node << 3) + (k2 << 1));
        const float w0 = __expf(lrelu(asL[g] + adn));
        float denom = w0;
        float a0 = w0 * bflo(us.x), a1 = w0 * bfhi(us.x);
        float a2 = w0 * bflo(us.y), a3 = w0 * bfhi(us.y);
        const int n = hist[g];
        const int* sp = srt + (scanv[g] - n);
        int i = 0;
        for (; i + 8 <= n; i += 8) {
            const int s0 = sp[i+0], s1 = sp[i+1], s2_ = sp[i+2], s3 = sp[i+3];
            const int s4 = sp[i+4], s5 = sp[i+5], s6 = sp[i+6], s7 = sp[i+7];
            const uint2 v0 = *(const uint2*)(hc + ((size_t)s0 << 3) + (k2 << 1));
            const uint2 v1 = *(const uint2*)(hc + ((size_t)s1 << 3) + (k2 << 1));
            const uint2 v2 = *(const uint2*)(hc + ((size_t)s2_ << 3) + (k2 << 1));
            const uint2 v3 = *(const uint2*)(hc + ((size_t)s3 << 3) + (k2 << 1));
            const uint2 v4 = *(const uint2*)(hc + ((size_t)s4 << 3) + (k2 << 1));
            const uint2 v5 = *(const uint2*)(hc + ((size_t)s5 << 3) + (k2 << 1));
            const uint2 v6 = *(const uint2*)(hc + ((size_t)s6 << 3) + (k2 << 1));
            const uint2 v7 = *(const uint2*)(hc + ((size_t)s7 << 3) + (k2 << 1));
            const float x0 = asrc[s0], x1 = asrc[s1], x2 = asrc[s2_], x3 = asrc[s3];
            const float x4 = asrc[s4], x5 = asrc[s5], x6 = asrc[s6], x7 = asrc[s7];
            const float e0 = __expf(lrelu(x0 + adn));
            const float e1 = __expf(lrelu(x1 + adn));
            const float e2 = __expf(lrelu(x2 + adn));
            const float e3 = __expf(lrelu(x3 + adn));
            const float e4 = __expf(lrelu(x4 + adn));
            const float e5 = __expf(lrelu(x5 + adn));
            const float e6 = __expf(lrelu(x6 + adn));
            const float e7 = __expf(lrelu(x7 + adn));
            denom += (e0 + e1 + e2 + e3) + (e4 + e5 + e6 + e7);
            a0 = fmaf(e0, bflo(v0.x), a0); a1 = fmaf(e0, bfhi(v0.x), a1);
            a2 = fmaf(e0, bflo(v0.y), a2); a3 = fmaf(e0, bfhi(v0.y), a3);
            a0 = fmaf(e1, bflo(v1.x), a0); a1 = fmaf(e1, bfhi(v1.x), a1);
            a2 = fmaf(e1, bflo(v1.y), a2); a3 = fmaf(e1, bfhi(v1.y), a3);
            a0 = fmaf(e2, bflo(v2.x), a0); a1 = fmaf(e2, bfhi(v2.x), a1);
            a2 = fmaf(e2, bflo(v2.y), a2); a3 = fmaf(e2, bfhi(v2.y), a3);
            a0 = fmaf(e3, bflo(v3.x), a0); a1 = fmaf(e3, bfhi(v3.x), a1);
            a2 = fmaf(e3, bflo(v3.y), a2); a3 = fmaf(e3, bfhi(v3.y), a3);
            a0 = fmaf(e4, bflo(v4.x), a0); a1 = fmaf(e4, bfhi(v4.x), a1);
            a2 = fmaf(e4, bflo(v4.y), a2); a3 = fmaf(e4, bfhi(v4.y), a3);
            a0 = fmaf(e5, bflo(v5.x), a0); a1 = fmaf(e5, bfhi(v5.x), a1);
            a2 = fmaf(e5, bflo(v5.y), a2); a3 = fmaf(e5, bfhi(v5.y), a3);
            a0 = fmaf(e6, bflo(v6.x), a0); a1 = fmaf(e6, bfhi(v6.x), a1);
            a2 = fmaf(e6, bflo(v6.y), a2); a3 = fmaf(e6, bfhi(v6.y), a3);
            a0 = fmaf(e7, bflo(v7.x), a0); a1 = fmaf(e7, bfhi(v7.x), a1);
            a2 = fmaf(e7, bflo(v7.y), a2); a3 = fmaf(e7, bfhi(v7.y), a3);
        }
        for (; i < n; ++i) {
            const int s = sp[i];
            const uint2 v = *(const uint2*)(hc + ((size_t)s << 3) + (k2 << 1));
            const float w = __expf(lrelu(asrc[s] + adn));
            denom += w;
            a0 = fmaf(w, bflo(v.x), a0); a1 = fmaf(w, bfhi(v.x), a1);
            a2 = fmaf(w, bflo(v.y), a2); a3 = fmaf(w, bfhi(v.y), a3);
        }
        const float inv = 1.f / denom;
        float4 o;
        o.x = a0 * inv + bl[K+0];
        o.y = a1 * inv + bl[K+1];
        o.z = a2 * inv + bl[K+2];
        o.w = a3 * inv + bl[K+3];
        *(float4*)(outp + ((size_t)node << 4) + K) = o;
    }
}

// ---------------------------------------------------------------------------
// Fallback kernels (round-3 proven atomic path, fp32 buffers) + diag
// ---------------------------------------------------------------------------
__global__ __launch_bounds__(256) void k_feat1(
    const void* __restrict__ x, const void* __restrict__ W1,
    const void* __restrict__ a_s, const void* __restrict__ a_d,
    const int* __restrict__ flags,
    float* __restrict__ hbuf, float* __restrict__ asrc, float* __restrict__ adst)
{
    const bool f32 = flags[0] & 1;
    __shared__ float Wl[F_IN * F_HID];
    __shared__ float asl[F_HID];
    __shared__ float adl[F_HID];
    const int t = threadIdx.x;
    for (int i = t; i < F_IN * F_HID; i += 256) Wl[i] = loadf(W1, i, f32);
    if (t < F_HID) { asl[t] = loadf(a_s, t, f32); adl[t] = loadf(a_d, t, f32); }
    __syncthreads();
    const int node = blockIdx.x * 256 + t;
    if (node >= N_NODES) return;
    float h[F_HID];
#pragma unroll
    for (int k = 0; k < F_HID; ++k) h[k] = 0.f;
    if (f32) {
        const float2* xp = (const float2*)((const float*)x + (size_t)node * F_IN);
#pragma unroll
        for (int j = 0; j < F_IN / 2; ++j) {
            const float2 v = xp[j];
#pragma unroll
            for (int k = 0; k < F_HID; ++k) {
                h[k] = fmaf(v.x, Wl[(2*j)   * F_HID + k], h[k]);
                h[k] = fmaf(v.y, Wl[(2*j+1) * F_HID + k], h[k]);
            }
        }
    } else {
        const unsigned* xu = (const unsigned*)x + (size_t)node * (F_IN / 2);
#pragma unroll
        for (int j = 0; j < F_IN / 2; ++j) {
            const unsigned u = xu[j];
            const float v0 = __uint_as_float(u << 16);
            const float v1 = __uint_as_float(u & 0xFFFF0000u);
#pragma unroll
            for (int k = 0; k < F_HID; ++k) {
                h[k] = fmaf(v0, Wl[(2*j)   * F_HID + k], h[k]);
                h[k] = fmaf(v1, Wl[(2*j+1) * F_HID + k], h[k]);
            }
        }
    }
    float s = 0.f, d = 0.f;
#pragma unroll
    for (int k = 0; k < F_HID; ++k) { s = fmaf(h[k], asl[k], s); d = fmaf(h[k], adl[k], d); }
    asrc[node] = s; adst[node] = d;
    float4* hb = (float4*)(hbuf + (size_t)node * F_HID);
#pragma unroll
    for (int q = 0; q < 4; ++q)
        hb[q] = make_float4(h[4*q], h[4*q+1], h[4*q+2], h[4*q+3]);
}

__global__ __launch_bounds__(256) void k_selfinit(
    const float* __restrict__ asrc, const float* __restrict__ adst,
    const float* __restrict__ h, float* __restrict__ denom, float* __restrict__ acc)
{
    const int t = blockIdx.x * 256 + threadIdx.x;
    if (t >= N_NODES * F_HID) return;
    const int n = t >> 4;
    const float w0 = __expf(lrelu(asrc[n] + adst[n]));
    if ((t & 15) == 0) denom[n] = w0;
    acc[t] = w0 * h[t];
}

__global__ __launch_bounds__(256) void k_edge(
    const void* __restrict__ ei, const int* __restrict__ flags,
    const float* __restrict__ asrc, const float* __restrict__ adst,
    const float* __restrict__ hbuf,
    float* __restrict__ denom, float* __restrict__ acc)
{
    const int e = blockIdx.x * 256 + threadIdx.x;
    if (e >= N_EDGES) return;
    int s, d;
    if (flags[0] & 2) {
        const long long* e64 = (const long long*)ei;
        s = (int)e64[e]; d = (int)e64[(size_t)N_EDGES + e];
    } else {
        const int* e32 = (const int*)ei;
        s = e32[e]; d = e32[(size_t)N_EDGES + e];
    }
    const float w = __expf(lrelu(asrc[s] + adst[d]));
    atomicAdd(&denom[d], w);
    const float4* hs = (const float4*)(hbuf + (size_t)s * F_HID);
    float* ad = acc + (size_t)d * F_HID;
#pragma unroll
    for (int q = 0; q < 4; ++q) {
        const float4 hv = hs[q];
        atomicAdd(ad + 4*q + 0, w * hv.x);
        atomicAdd(ad + 4*q + 1, w * hv.y);
        atomicAdd(ad + 4*q + 2, w * hv.z);
        atomicAdd(ad + 4*q + 3, w * hv.w);
    }
}

__global__ __launch_bounds__(256) void k_div_elu(
    float* __restrict__ acc, const float* __restrict__ denom,
    const void* __restrict__ b1, const int* __restrict__ flags)
{
    const bool f32 = flags[0] & 1;
    const int t = blockIdx.x * 256 + threadIdx.x;
    if (t >= N_NODES * F_HID) return;
    const float v = acc[t] / denom[t >> 4] + loadf(b1, t & 15, f32);
    acc[t] = v > 0.f ? v : expm1f(v);
}

__global__ __launch_bounds__(256) void k_mid(
    const float* __restrict__ z,
    const void* __restrict__ W2, const void* __restrict__ a_s2,
    const void* __restrict__ a_d2, const int* __restrict__ flags,
    float* __restrict__ h2, float* __restrict__ asrc, float* __restrict__ adst)
{
    const bool f32 = flags[0] & 1;
    __shared__ float Wl[F_HID * F_HID];
    __shared__ float asl[F_HID];
    __shared__ float adl[F_HID];
    const int t = threadIdx.x;
    if (t < F_HID * F_HID) Wl[t] = loadf(W2, t, f32);
    if (t < F_HID) { asl[t] = loadf(a_s2, t, f32); adl[t] = loadf(a_d2, t, f32); }
    __syncthreads();
    const int node = blockIdx.x * 256 + t;
    if (node >= N_NODES) return;
    float zr[F_HID];
    const float4* zi = (const float4*)(z + (size_t)node * F_HID);
#pragma unroll
    for (int q = 0; q < 4; ++q) {
        const float4 zv = zi[q];
        zr[4*q+0]=zv.x; zr[4*q+1]=zv.y; zr[4*q+2]=zv.z; zr[4*q+3]=zv.w;
    }
    float h[F_HID];
#pragma unroll
    for (int k = 0; k < F_HID; ++k) h[k] = 0.f;
#pragma unroll
    for (int j = 0; j < F_HID; ++j) {
        const float zv = zr[j];
#pragma unroll
        for (int k = 0; k < F_HID; ++k) h[k] = fmaf(zv, Wl[j * F_HID + k], h[k]);
    }
    float s = 0.f, d = 0.f;
#pragma unroll
    for (int k = 0; k < F_HID; ++k) { s = fmaf(h[k], asl[k], s); d = fmaf(h[k], adl[k], d); }
    asrc[node] = s; adst[node] = d;
    float4* hb = (float4*)(h2 + (size_t)node * F_HID);
#pragma unroll
    for (int q = 0; q < 4; ++q)
        hb[q] = make_float4(h[4*q], h[4*q+1], h[4*q+2], h[4*q+3]);
}

__global__ __launch_bounds__(256) void k_out(
    const float* __restrict__ acc, const float* __restrict__ denom,
    const void* __restrict__ b2, const int* __restrict__ flags,
    float* __restrict__ out)
{
    const bool f32 = flags[0] & 1;
    const int t = blockIdx.x * 256 + threadIdx.x;
    if (t >= N_NODES * F_HID) return;
    out[t] = acc[t] / denom[t >> 4] + loadf(b2, t & 15, f32);
}

__global__ __launch_bounds__(256) void k_diag(float* __restrict__ out, float v)
{
    const int t = blockIdx.x * 256 + threadIdx.x;
    if (t < N_NODES * F_HID) out[t] = v;
}

extern "C" void kernel_launch(void* const* d_in, const int* in_sizes, int n_in,
                              void* d_out, int out_size, void* d_ws, size_t ws_size,
                              hipStream_t stream) {
    const void* x   = d_in[0];
    const void* ei  = d_in[1];
    const void* W1  = d_in[2];
    const void* a1s = d_in[3];
    const void* a1d = d_in[4];
    const void* b1  = d_in[5];
    const void* W2  = d_in[6];
    const void* a2s = d_in[7];
    const void* a2d = d_in[8];
    const void* b2  = d_in[9];
    float* out = (float*)d_out;

    float* ws = (float*)d_ws;
    int*      flags  = (int*)(ws + WS_FLAGS);
    float*    adst   = ws + WS_ADST;
    float*    adst2  = ws + WS_ADST2;
    int*      bcnt   = (int*)(ws + WS_BCNT);
    float*    asrc1  = ws + WS_ASRC1;
    float*    asrc2  = ws + WS_ASRC2;
    unsigned* hc1    = (unsigned*)(ws + WS_HC1);
    unsigned* hc2    = (unsigned*)(ws + WS_HC2);
    int*      bedges = (int*)(ws + WS_BEDGES);

    const dim3 blk(256);
    const dim3 grdN((N_NODES + 255) / 256);
    const dim3 grdE((N_EDGES + 255) / 256);
    const dim3 grdO((N_NODES * F_HID + 255) / 256);
    const dim3 grdBF(GRDB + GRDN_F);
    const dim3 grdB(NBUCK);

    if (ws_size >= WS_BUCKET_END * 4) {
        k_probe0 <<<dim3(1), blk, 0, stream>>>(x, ei, flags, bcnt);
        k_binfeat<<<grdBF, dim3(BTHR), 0, stream>>>(ei, x, W1, a1s, a1d, flags,
                                                    bcnt, bedges, hc1, asrc1, adst);
        k_agg1   <<<grdB, dim3(512), 0, stream>>>(bcnt, bedges, asrc1, adst, hc1,
                                                  b1, W2, a2s, a2d, flags,
                                                  hc2, asrc2, adst2);
        k_agg2   <<<grdB, dim3(512), 0, stream>>>(bcnt, bedges, asrc2, adst2, hc2,
                                                  b2, flags, out);
    } else if (ws_size >= WS_ATOMIC_END * 4) {
        float* fb_h   = ws + WS_HC1;     // 1.6M fp32
        float* fb_acc = ws + WS_HC2;     // 1.6M fp32
        float* fb_den = ws + WS_FB_DEN;  // 100k
        float* fb_as  = ws + WS_FB_AS;   // 100k
        float* fb_ad  = ws + WS_ADST;
        k_probe0 <<<dim3(1), blk, 0, stream>>>(x, ei, flags, bcnt);
        k_feat1  <<<grdN, blk, 0, stream>>>(x, W1, a1s, a1d, flags, fb_h, fb_as, fb_ad);
        k_selfinit<<<grdO, blk, 0, stream>>>(fb_as, fb_ad, fb_h, fb_den, fb_acc);
        k_edge   <<<grdE, blk, 0, stream>>>(ei, flags, fb_as, fb_ad, fb_h, fb_den, fb_acc);
        k_div_elu<<<grdO, blk, 0, stream>>>(fb_acc, fb_den, b1, flags);
        k_mid    <<<grdN, blk, 0, stream>>>(fb_acc, W2, a2s, a2d, flags, fb_h, fb_as, fb_ad);
        k_selfinit<<<grdO, blk, 0, stream>>>(fb_as, fb_ad, fb_h, fb_den, fb_acc);
        k_edge   <<<grdE, blk, 0, stream>>>(ei, flags, fb_as, fb_ad, fb_h, fb_den, fb_acc);
        k_out    <<<grdO, blk, 0, stream>>>(fb_acc, fb_den, b2, flags, out);
    } else {
        k_diag<<<grdO, blk, 0, stream>>>(out, (float)(ws_size >> 10));
    }
}